// Round 10
// baseline (118.853 us; speedup 1.0000x reference)
//
#include <hip/hip_runtime.h>
#include <hip/hip_bf16.h>

// MultiHeadAttentionLegacy: B=2, S=2048, E=768, H=12, HD=64, G=B*H=24
// Inputs fp32, output fp32; internal bf16 MFMA pipeline.
// Legacy reshape = pure flat re-chunk: [4096][768] buffer == 24 slabs [2048][64].
//   Element (row, hh*64+d) -> sidx = row*12+hh, slab g = sidx>>11, k = sidx&2047.
//   (NOT the transpose-based split g=(row>>11)*12+hh -- that was R8/R9's bug.)
// Softmax denominator over FULL row; tril mask applied AFTER softmax.
// Q projection pre-scaled by log2(e)/sqrt(64) so attention uses exp2 directly.
//
// R1: pre-convert q/k/v fp32->bf16 (gll staging for both GEMM operands).
// R2 (FAILED): deeper attn LDS pipeline -> worse. Not latency-bound.
// R3 (FAILED): direct per-lane L2 reads -> 2x worse. LDS staging is right.
// R4 (FAILED): fewer rounds via tail-pairing -> slightly worse.
// R5 (WIN): constant-sum bx triplets balance per-CU PV load; XCD-affine GEMM.
// R6 (small WIN): launch_bounds(256,3) + hoisted LDS offsets.
// R7 (small WIN): s_sleep slot stagger (anti-convoy).
// R8 (FAILED correctness): 4 changes at once; couldn't localize.
// R9 BISECT: reverted both main loops to R7 sync -> SAME absmax 6.909e-02
//   => vt epilogue mapping indicted (prelude fusion exonerated).
// R10: vt epilogue fixed to the true legacy mapping (per-element stores at
//   k-stride 12 -- vectorized k-contiguous stores are impossible under the
//   flat re-chunk). Everything else identical to R9/R7-proven structures.

typedef __bf16 bf16;
typedef __attribute__((ext_vector_type(4))) __bf16 bf16x4;
typedef __attribute__((ext_vector_type(8))) __bf16 bf16x8;
typedef __attribute__((ext_vector_type(4))) float f32x4;
typedef __attribute__((ext_vector_type(16))) float f32x16;
typedef __attribute__((ext_vector_type(4))) unsigned int uint4v;

#define MFMA16(a,b,c) __builtin_amdgcn_mfma_f32_16x16x32_bf16((a),(b),(c),0,0,0)
#define MFMA32(a,b,c) __builtin_amdgcn_mfma_f32_32x32x16_bf16((a),(b),(c),0,0,0)

typedef const __attribute__((address_space(1))) unsigned int GU32;
typedef __attribute__((address_space(3))) unsigned int LU32;

__device__ __forceinline__ void gll16(const void* gsrc, void* ldst) {
    __builtin_amdgcn_global_load_lds((GU32*)gsrc, (LU32*)ldst, 16, 0, 0);
}

__device__ __forceinline__ unsigned pk_bf16(float lo, float hi) {
    unsigned r;
    asm("v_cvt_pk_bf16_f32 %0, %1, %2" : "=v"(r) : "v"(lo), "v"(hi));
    return r;
}

// v_permlane32_swap_b32: a.hi32lanes <-> b.lo32lanes
__device__ __forceinline__ void plane32swap(unsigned &a, unsigned &b) {
    asm("v_permlane32_swap_b32 %0, %1" : "+v"(a), "+v"(b));
}

__device__ __forceinline__ bf16x8 frag_words(unsigned w0, unsigned w1, unsigned w2, unsigned w3) {
    union { unsigned u[4]; bf16x8 v; } f;
    f.u[0] = w0; f.u[1] = w1; f.u[2] = w2; f.u[3] = w3;
    return f.v;
}

// ------- fused prelude: cvt (blocks 0..4607) + weight transpose (4608..5183) -------
struct TArg { const float* in; bf16* out; };

__global__ __launch_bounds__(256) void prelude(
    const float* __restrict__ q, const float* __restrict__ k, const float* __restrict__ v,
    bf16* __restrict__ Qb, bf16* __restrict__ Kb, bf16* __restrict__ Vb,
    TArg a0, TArg a1, TArg a2, TArg a3)
{
    __shared__ bf16 tile[64][72];
    const int b = blockIdx.x;
    const int tid = threadIdx.x;
    if (b < 4608) {
        const int m = b / 1536, xx = b % 1536;
        const float* src = m == 0 ? q : m == 1 ? k : v;
        bf16* dst = m == 0 ? Qb : m == 1 ? Kb : Vb;
        const size_t base = (size_t)xx * 2048 + (size_t)tid * 8;
        f32x4 lo = *(const f32x4*)&src[base];
        f32x4 hi = *(const f32x4*)&src[base + 4];
        bf16x8 o;
        for (int j = 0; j < 4; ++j) { o[j] = (bf16)lo[j]; o[4 + j] = (bf16)hi[j]; }
        *(bf16x8*)&dst[base] = o;
    } else {
        const int bb = b - 4608;                // 0..575
        const int wz = bb / 144, bxy = bb % 144;
        TArg ta = wz == 0 ? a0 : wz == 1 ? a1 : wz == 2 ? a2 : a3;
        const int bx = bxy % 12, by = bxy / 12;
        const int k0 = by * 64, n0 = bx * 64;
        for (int qq = 0; qq < 2; ++qq) {
            int idx = qq * 256 + tid;
            int i = idx >> 3, j0 = (idx & 7) * 8;
            const float* src = &ta.in[(size_t)(k0 + i) * 768 + n0 + j0];
            f32x4 lo = *(const f32x4*)&src[0];
            f32x4 hi = *(const f32x4*)&src[4];
            bf16x8 vv;
            for (int j = 0; j < 4; ++j) { vv[j] = (bf16)lo[j]; vv[4 + j] = (bf16)hi[j]; }
            *(bf16x8*)&tile[i][j0] = vv;
        }
        __syncthreads();
        for (int qq = 0; qq < 2; ++qq) {
            int idx = qq * 256 + tid;
            int n = idx >> 3, j0 = (idx & 7) * 8;
            bf16x8 vv;
            for (int jj = 0; jj < 8; ++jj) vv[jj] = tile[j0 + jj][n];
            *(bf16x8*)&ta.out[(size_t)(n0 + n) * 768 + k0 + j0] = vv;
        }
    }
}

// --- GEMM: C[4096x768] = (A @ Bt^T + bias) * scale.  A is bf16 always.
//     MODE 0: C bf16 (proj);  MODE 1: C fp32 (out)
//     vt=1 (V matrix): write C in legacy-slab-transposed layout Vt[g][d][k]
//       with g = (row*12+hh)>>11, k = (row*12+hh)&2047 (per-element stores).
//     R5: XCD-affine block remap. Loop = R7-proven __syncthreads two-phase. ---
struct GArg { const bf16* A; const bf16* Bt; const float* bias; void* C; float scale; int vt; };

template<int MODE>
__global__ __launch_bounds__(256) void gemm_bt_bias(GArg g0, GArg g1, GArg g2) {
    const int flat = blockIdx.x + 6 * blockIdx.y + 192 * blockIdx.z;
    const int xcd = flat & 7;
    const int idx = flat >> 3;          // z=3: 0..71, z=1: 0..23
    const int mat = idx / 24;
    const int rem = idx % 24;
    const int rloc = rem / 6, colb = rem % 6;
    GArg ga = mat == 0 ? g0 : mat == 1 ? g1 : g2;
    const int K = 768, N = 768;
    __shared__ bf16 As[2][128][64];
    __shared__ bf16 Bs[2][128][64];
    const int tid = threadIdx.x;
    const int lane = tid & 63, wave = tid >> 6;
    const int l15 = lane & 15, lg = lane >> 4;
    const int r0 = (xcd * 4 + rloc) * 128, c0 = colb * 128;
    const int wr = (wave >> 1) * 64, wc = (wave & 1) * 64;
    f32x4 acc[4][4] = {};

    const int grow = wave * 8 + (lane >> 3);
    const int gcol = 8 * ((lane & 7) ^ (lane >> 3));

    auto stage = [&](int kt, int buf) {
        for (int i = 0; i < 4; ++i)
            gll16(&ga.A[(size_t)(r0 + i * 32 + grow) * K + kt + gcol], &As[buf][i * 32 + wave * 8][0]);
        for (int i = 0; i < 4; ++i)
            gll16(&ga.Bt[(size_t)(c0 + i * 32 + grow) * K + kt + gcol], &Bs[buf][i * 32 + wave * 8][0]);
    };

    stage(0, 0);
    __syncthreads();

    for (int c = 0; c < 12; ++c) {
        const int buf = c & 1;
        if (c < 11) stage((c + 1) * 64, buf ^ 1);   // fire-and-forget, drained at barrier
        for (int kk = 0; kk < 2; ++kk) {
            bf16x8 af[4], bfr[4];
            for (int i = 0; i < 4; ++i) {
                int row = wr + i * 16 + l15;
                af[i] = *(const bf16x8*)&As[buf][row][(kk * 32 + lg * 8) ^ ((row & 7) * 8)];
            }
            for (int j = 0; j < 4; ++j) {
                int row = wc + j * 16 + l15;
                bfr[j] = *(const bf16x8*)&Bs[buf][row][(kk * 32 + lg * 8) ^ ((row & 7) * 8)];
            }
            __builtin_amdgcn_s_setprio(1);
            for (int i = 0; i < 4; ++i)
                for (int j = 0; j < 4; ++j)
                    acc[i][j] = MFMA16(af[i], bfr[j], acc[i][j]);
            __builtin_amdgcn_s_setprio(0);
        }
        __syncthreads();
    }

    if (MODE == 0 && ga.vt) {
        // Legacy flat re-chunk: element (row,col=hh*64+d) -> sidx=row*12+hh,
        // slab g=sidx>>11, k=sidx&2047. Write Vt[g*131072 + d*2048 + k].
        // k-stride across r is 12 -> per-element stores (no vectorization).
        for (int j = 0; j < 4; ++j) {
            int col = c0 + wc + j * 16 + l15;
            float bv = ga.bias[col];
            const int hh = col >> 6, d = col & 63;
            for (int i = 0; i < 4; ++i) {
                int row = r0 + wr + i * 16 + lg * 4;
                for (int r = 0; r < 4; ++r) {
                    int sidx = (row + r) * 12 + hh;
                    int gq = sidx >> 11, kq = sidx & 2047;
                    ((bf16*)ga.C)[(size_t)gq * 131072 + (size_t)d * 2048 + kq] =
                        (bf16)(acc[i][j][r] + bv);
                }
            }
        }
        return;
    }
    for (int j = 0; j < 4; ++j) {
        int col = c0 + wc + j * 16 + l15;
        float bv = ga.bias[col];
        for (int i = 0; i < 4; ++i) {
            int row = r0 + wr + i * 16 + lg * 4;
            for (int r = 0; r < 4; ++r) {
                float val = (acc[i][j][r] + bv) * ga.scale;
                if constexpr (MODE == 0)
                    ((bf16*)ga.C)[(size_t)(row + r) * N + col] = (bf16)val;
                else
                    ((float*)ga.C)[(size_t)(row + r) * N + col] = val;
            }
        }
    }
}

// ------- attention v13: R7-proven loop structure (vmcnt(0) + one barrier) -------
// Block = 4 waves over 64 q-rows. Wave (wq=w>>1, p=w&1): q rows t0+wq*32..+31,
// k-half p of each 64-chunk. Swapped QK: S-regs q=lane&31, k=(r&3)+8*(r>>2)+4*hi.
// bid mapping: xcd = bid&7 keeps K/V L2-local; constant-sum bx permutations
// across slots; s_sleep slot stagger (anti-convoy); hoisted LDS offsets.
__global__ __launch_bounds__(256, 3) void attn_kernel(
    const bf16* __restrict__ Qp, const bf16* __restrict__ Kp,
    const bf16* __restrict__ Vtg, bf16* __restrict__ Ob)
{
    const int bid = blockIdx.x;
    const int xcd = bid & 7;
    const int idx = bid >> 3;            // 0..95
    const int t = idx & 31, s = idx >> 5;
    const int bx = (s == 0) ? (31 - t)
                 : (s == 1) ? ((15 - t) & 31)
                 : (((t << 1) & 31) | (t >> 4));
    const int g = xcd * 3 + s;
    const int t0 = bx * 64;
    const int tid = threadIdx.x, lane = tid & 63, w = tid >> 6;
    const int wq = w >> 1, p = w & 1;
    const int l31 = lane & 31, hi = lane >> 5;

    // anti-convoy stagger: co-resident slots offset ~512*s cycles
    if (s == 1) __builtin_amdgcn_s_sleep(8);
    else if (s == 2) __builtin_amdgcn_s_sleep(16);

    __shared__ __align__(16) char smem[32768];
    bf16* KsE = (bf16*)smem;                 // [2][64][64] d-swizzled
    bf16* VsE = (bf16*)(smem + 16384);       // [2][64][64] V^T, k-swizzled

    const bf16* Qg = Qp + (size_t)g * 131072;
    const bf16* Kg = Kp + (size_t)g * 131072;
    const bf16* Vg = Vtg + (size_t)g * 131072;   // [64][2048]
    bf16* Og = Ob + (size_t)g * 131072;

    // Q B-frags in registers: col=q=l31, k-dim d = m*16 + hi*8 + j
    const int qrow = t0 + wq * 32 + l31;
    bf16x8 qB[4];
    for (int m = 0; m < 4; ++m)
        qB[m] = *(const bf16x8*)&Qg[(size_t)qrow * 64 + m * 16 + hi * 8];

    // staging: wave stages 16 rows (2 gll of 8 rows), pre-swizzled source col
    const int srow = w * 16 + (lane >> 3);
    const int scol = 8 * ((lane & 7) ^ (lane >> 3));
    auto stageK = [&](int ch, int b2) {
        const bf16* src = &Kg[(size_t)(ch * 64 + srow) * 64 + scol];
        bf16* dst = KsE + b2 * 4096 + w * 16 * 64;
        gll16(src, dst);
        gll16(src + 8 * 64, dst + 8 * 64);
    };
    auto stageV = [&](int ch, int b2) {
        const bf16* src = &Vg[(size_t)srow * 2048 + ch * 64 + scol];
        bf16* dst = VsE + b2 * 4096 + w * 16 * 64;
        gll16(src, dst);
        gll16(src + 8 * 2048, dst + 8 * 64);
    };

    stageK(0, 0);
    stageV(0, 0);

    f32x16 oacc0 = {}, oacc1 = {};
    float dsum = 0.f;
    const int qmax = t0 + wq * 32 + 31;                 // wave's q range top
    const int qmin = t0 + wq * 32;
    const int kofs = p * 32;                            // wave's k-half offset
    const int swz = (l31 & 7) * 8;

    // hoisted per-lane LDS element offsets (loop-invariant; buffer = +4096)
    int koff[4], voff0[2], voff1[2];
    for (int m = 0; m < 4; ++m)
        koff[m] = (kofs + l31) * 64 + ((m * 16 + hi * 8) ^ swz);
    for (int kt = 0; kt < 2; ++kt) {
        const int col = (kofs + kt * 16 + hi * 8) ^ swz;
        voff0[kt] = l31 * 64 + col;
        voff1[kt] = (32 + l31) * 64 + col;
    }

    for (int c = 0; c < 32; ++c) {
        const int boff = (c & 1) * 4096;
        asm volatile("s_waitcnt vmcnt(0)" ::: "memory");
        __builtin_amdgcn_s_barrier();
        __builtin_amdgcn_sched_barrier(0);
        if (c < 31) {
            stageK(c + 1, (c & 1) ^ 1);
            if (c + 1 <= bx) stageV(c + 1, (c & 1) ^ 1);
        }
        __builtin_amdgcn_sched_barrier(0);

        const int kc = c * 64;
        const bool activ = (kc + kofs <= qmax);         // wave-uniform
        const bool fullc = (kc + kofs + 31 <= qmin);    // wave-uniform

        // ---- QK^T: A = K rows (wave's 32-k half), B = Q regs
        f32x16 s2 = {};
        __builtin_amdgcn_s_setprio(1);
        for (int m = 0; m < 4; ++m) {
            bf16x8 kf = *(const bf16x8*)&KsE[boff + koff[m]];
            s2 = MFMA32(kf, qB[m], s2);
        }
        __builtin_amdgcn_s_setprio(0);

        // ---- exp2 (Q pre-scaled by log2e/8) + denominator (UNmasked, tree sum)
        float e[16];
        for (int r = 0; r < 16; ++r) e[r] = __builtin_exp2f(s2[r]);
        {
            float p01 = e[0] + e[1],  p23 = e[2] + e[3];
            float p45 = e[4] + e[5],  p67 = e[6] + e[7];
            float p89 = e[8] + e[9],  pab = e[10] + e[11];
            float pcd = e[12] + e[13], pef = e[14] + e[15];
            float q0 = p01 + p23, q1 = p45 + p67, q2 = p89 + pab, q3 = pcd + pef;
            dsum += (q0 + q1) + (q2 + q3);
        }

        if (activ) {
            if (!fullc) {   // diagonal: tril AFTER softmax
                for (int r = 0; r < 16; ++r) {
                    int kg = kc + kofs + (r & 3) + 8 * (r >> 2) + 4 * hi;
                    if (kg > qrow) e[r] = 0.f;
                }
            }
            // ---- pack P to bf16 + permlane32_swap -> 2 PV A-frags, no LDS
            bf16x8 pf[2];
            {
                unsigned a0 = pk_bf16(e[0], e[1]), a1 = pk_bf16(e[2], e[3]);
                unsigned b0 = pk_bf16(e[4], e[5]), b1 = pk_bf16(e[6], e[7]);
                plane32swap(a0, b0); plane32swap(a1, b1);
                pf[0] = frag_words(a0, a1, b0, b1);
                a0 = pk_bf16(e[8], e[9]);   a1 = pk_bf16(e[10], e[11]);
                b0 = pk_bf16(e[12], e[13]); b1 = pk_bf16(e[14], e[15]);
                plane32swap(a0, b0); plane32swap(a1, b1);
                pf[1] = frag_words(a0, a1, b0, b1);
            }
            // ---- PV: A = P frags, B = V^T tile (col d, row k)
            __builtin_amdgcn_s_setprio(1);
            for (int kt = 0; kt < 2; ++kt) {
                bf16x8 v0 = *(const bf16x8*)&VsE[boff + voff0[kt]];
                bf16x8 v1 = *(const bf16x8*)&VsE[boff + voff1[kt]];
                oacc0 = MFMA32(pf[kt], v0, oacc0);
                oacc1 = MFMA32(pf[kt], v1, oacc1);
            }
            __builtin_amdgcn_s_setprio(0);
        }
    }

    // ---- wave-internal k reduce: lane & lane^32 hold complementary k for q=l31
    dsum += __shfl_xor(dsum, 32);

    // ---- cross-pair reduce via LDS overlay (Ks/Vs regions dead after loop)
    __syncthreads();
    float* Ored = (float*)smem;                 // [pair][q 0-31][d 0-63] = 2 x 8KB
    float* dred = (float*)(smem + 16384);       // [wave][q 0-31] = 512 B
    if (l31 == lane) dred[w * 32 + l31] = dsum; // lanes 0-31 only
    if (p == 1) {
        float* Op = Ored + wq * 2048;
        for (int r = 0; r < 16; ++r) {
            const int qoff = (r & 3) + 8 * (r >> 2) + 4 * hi;
            Op[qoff * 64 + l31]      = oacc0[r];
            Op[qoff * 64 + 32 + l31] = oacc1[r];
        }
    }
    __syncthreads();
    if (p == 0) {
        const float dtot = dsum + dred[(w + 1) * 32 + l31];
        const float rall = 1.0f / dtot;          // valid for q=l31 at every lane
        const float* Op = Ored + wq * 2048;
        for (int r = 0; r < 16; ++r) {
            const int qoff = (r & 3) + 8 * (r >> 2) + 4 * hi;
            const float inv = __shfl(rall, qoff);
            const size_t row = (size_t)(t0 + wq * 32 + qoff) * 64;
            Og[row + l31]      = (bf16)((oacc0[r] + Op[qoff * 64 + l31])      * inv);
            Og[row + 32 + l31] = (bf16)((oacc1[r] + Op[qoff * 64 + 32 + l31]) * inv);
        }
    }
}

// ---------------- host ----------------
extern "C" void kernel_launch(void* const* d_in, const int* in_sizes, int n_in,
                              void* d_out, int out_size, void* d_ws, size_t ws_size,
                              hipStream_t stream) {
    const float* query = (const float*)d_in[0];
    const float* key_  = (const float*)d_in[1];
    const float* value = (const float*)d_in[2];
    const float* Wq = (const float*)d_in[3];
    const float* bq = (const float*)d_in[4];
    const float* Wk = (const float*)d_in[5];
    const float* bk = (const float*)d_in[6];
    const float* Wv = (const float*)d_in[7];
    const float* bv = (const float*)d_in[8];
    const float* Wo = (const float*)d_in[9];
    const float* bo = (const float*)d_in[10];
    float* out = (float*)d_out;

    const size_t MN = (size_t)4096 * 768;
    const size_t WW = (size_t)768 * 768;
    bf16* Qp  = (bf16*)d_ws;
    bf16* Kp  = Qp + MN;
    bf16* Vt  = Kp + MN;     // V projection written in legacy-slab V^T layout (vt=1)
    bf16* Obf = Vt + MN;
    bf16* Sp1 = Obf + MN;    // spare slab — aliased by Kb below
    bf16* WtQ = Sp1 + MN;
    bf16* WtK = WtQ + WW;
    bf16* WtV = WtK + WW;
    bf16* WtO = WtV + WW;
    bf16* Vb  = WtO + WW;    // +1 MN slab
    // bf16 activation inputs alias slabs that are dead until after gemm<0>:
    bf16* Qb  = Obf;         // Obf written only by attn (after gemm<0> reads Qb)
    bf16* Kb  = Sp1;         // spare slab

    prelude<<<dim3(5184), 256, 0, stream>>>(
        query, key_, value, Qb, Kb, Vb,
        TArg{Wq, WtQ}, TArg{Wk, WtK}, TArg{Wv, WtV}, TArg{Wo, WtO});

    // fold log2(e)/sqrt(HD) into Q so attention uses native exp2;
    // V written directly in legacy-slab transposed layout (vt=1)
    gemm_bt_bias<0><<<dim3(6, 32, 3), 256, 0, stream>>>(
        GArg{Qb, WtQ, bq, Qp, 0.18033688f, 0},
        GArg{Kb, WtK, bk, Kp, 1.0f, 0},
        GArg{Vb, WtV, bv, Vt, 1.0f, 1});

    attn_kernel<<<dim3(768), 256, 0, stream>>>(Qp, Kp, Vt, Obf);

    gemm_bt_bias<1><<<dim3(6, 32, 1), 256, 0, stream>>>(
        GArg{Obf, WtO, bo, out, 1.0f, 0},
        GArg{Obf, WtO, bo, out, 1.0f, 0},
        GArg{Obf, WtO, bo, out, 1.0f, 0});
}

// Round 11
// 106.607 us; speedup vs baseline: 1.1149x; 1.1149x over previous
//
#include <hip/hip_runtime.h>
#include <hip/hip_bf16.h>

// MultiHeadAttentionLegacy: B=2, S=2048, E=768, H=12, HD=64, G=B*H=24
// Inputs fp32, output fp32; internal bf16 MFMA pipeline.
// Legacy reshape = pure flat re-chunk: [4096][768] buffer == 24 slabs [2048][64].
// Softmax denominator over FULL row; tril mask applied AFTER softmax.
// Q projection pre-scaled by log2(e)/sqrt(64) so attention uses exp2 directly.
//
// R1: pre-convert q/k/v fp32->bf16 (gll staging for both GEMM operands).
// R2 (FAILED): deeper attn LDS pipeline -> worse. Not latency-bound.
// R3 (FAILED): direct per-lane L2 reads -> 2x worse. LDS staging is right.
// R4 (FAILED): fewer rounds via tail-pairing -> slightly worse.
// R5 (WIN): constant-sum bx triplets balance per-CU PV load; XCD-affine GEMM.
// R6 (small WIN): launch_bounds(256,3) + hoisted LDS offsets.
// R7 (small WIN): s_sleep slot stagger (anti-convoy).
// R8/R9 (FAILED): vt-fused V epilogue had wrong legacy mapping.
// R10 (passed, SLOW): correct vt mapping needs stride-12 2B scatter stores --
//   structurally uncoalescable in any col-blocked epilogue (contiguous k ==
//   all 12 heads == all 768 cols). gemm dispatch 28->53us. Fused-vt is dead.
// R11: revert to separate vtrans (flat re-chunk makes it coalesced both ways
//   via LDS transpose); keep prelude fusion (exonerated by R10's pass).

typedef __bf16 bf16;
typedef __attribute__((ext_vector_type(4))) __bf16 bf16x4;
typedef __attribute__((ext_vector_type(8))) __bf16 bf16x8;
typedef __attribute__((ext_vector_type(4))) float f32x4;
typedef __attribute__((ext_vector_type(16))) float f32x16;
typedef __attribute__((ext_vector_type(4))) unsigned int uint4v;

#define MFMA16(a,b,c) __builtin_amdgcn_mfma_f32_16x16x32_bf16((a),(b),(c),0,0,0)
#define MFMA32(a,b,c) __builtin_amdgcn_mfma_f32_32x32x16_bf16((a),(b),(c),0,0,0)

typedef const __attribute__((address_space(1))) unsigned int GU32;
typedef __attribute__((address_space(3))) unsigned int LU32;

__device__ __forceinline__ void gll16(const void* gsrc, void* ldst) {
    __builtin_amdgcn_global_load_lds((GU32*)gsrc, (LU32*)ldst, 16, 0, 0);
}

__device__ __forceinline__ unsigned pk_bf16(float lo, float hi) {
    unsigned r;
    asm("v_cvt_pk_bf16_f32 %0, %1, %2" : "=v"(r) : "v"(lo), "v"(hi));
    return r;
}

// v_permlane32_swap_b32: a.hi32lanes <-> b.lo32lanes
__device__ __forceinline__ void plane32swap(unsigned &a, unsigned &b) {
    asm("v_permlane32_swap_b32 %0, %1" : "+v"(a), "+v"(b));
}

__device__ __forceinline__ bf16x8 frag_words(unsigned w0, unsigned w1, unsigned w2, unsigned w3) {
    union { unsigned u[4]; bf16x8 v; } f;
    f.u[0] = w0; f.u[1] = w1; f.u[2] = w2; f.u[3] = w3;
    return f.v;
}

// ------- fused prelude: cvt (blocks 0..4607) + weight transpose (4608..5183) -------
struct TArg { const float* in; bf16* out; };

__global__ __launch_bounds__(256) void prelude(
    const float* __restrict__ q, const float* __restrict__ k, const float* __restrict__ v,
    bf16* __restrict__ Qb, bf16* __restrict__ Kb, bf16* __restrict__ Vb,
    TArg a0, TArg a1, TArg a2, TArg a3)
{
    __shared__ bf16 tile[64][72];
    const int b = blockIdx.x;
    const int tid = threadIdx.x;
    if (b < 4608) {
        const int m = b / 1536, xx = b % 1536;
        const float* src = m == 0 ? q : m == 1 ? k : v;
        bf16* dst = m == 0 ? Qb : m == 1 ? Kb : Vb;
        const size_t base = (size_t)xx * 2048 + (size_t)tid * 8;
        f32x4 lo = *(const f32x4*)&src[base];
        f32x4 hi = *(const f32x4*)&src[base + 4];
        bf16x8 o;
        for (int j = 0; j < 4; ++j) { o[j] = (bf16)lo[j]; o[4 + j] = (bf16)hi[j]; }
        *(bf16x8*)&dst[base] = o;
    } else {
        const int bb = b - 4608;                // 0..575
        const int wz = bb / 144, bxy = bb % 144;
        TArg ta = wz == 0 ? a0 : wz == 1 ? a1 : wz == 2 ? a2 : a3;
        const int bx = bxy % 12, by = bxy / 12;
        const int k0 = by * 64, n0 = bx * 64;
        for (int qq = 0; qq < 2; ++qq) {
            int idx = qq * 256 + tid;
            int i = idx >> 3, j0 = (idx & 7) * 8;
            const float* src = &ta.in[(size_t)(k0 + i) * 768 + n0 + j0];
            f32x4 lo = *(const f32x4*)&src[0];
            f32x4 hi = *(const f32x4*)&src[4];
            bf16x8 vv;
            for (int j = 0; j < 4; ++j) { vv[j] = (bf16)lo[j]; vv[4 + j] = (bf16)hi[j]; }
            *(bf16x8*)&tile[i][j0] = vv;
        }
        __syncthreads();
        for (int qq = 0; qq < 2; ++qq) {
            int idx = qq * 256 + tid;
            int n = idx >> 3, j0 = (idx & 7) * 8;
            bf16x8 vv;
            for (int jj = 0; jj < 8; ++jj) vv[jj] = tile[j0 + jj][n];
            *(bf16x8*)&ta.out[(size_t)(n0 + n) * 768 + k0 + j0] = vv;
        }
    }
}

// ------- V slab transpose: Vt[g][d][k] = Vp_flat[g*131072 + k*64 + d] -------
// Exploits the flat re-chunk: the [4096][768] V projection buffer, viewed
// flat, IS 24 contiguous [2048][64] slabs. Coalesced reads + LDS transpose
// + coalesced writes. (The fused-GEMM version of this is impossible: k-stride
// is 12 in any col-blocked epilogue -- see R10.)
__global__ __launch_bounds__(256) void vtrans(const bf16* __restrict__ Vp, bf16* __restrict__ Vt) {
    __shared__ bf16 tile[64][72];
    const int g = blockIdx.y;
    const int k0 = blockIdx.x * 64;
    const bf16* src = Vp + (size_t)g * 131072;
    bf16* dst = Vt + (size_t)g * 131072;
    const int tid = threadIdx.x;
    for (int q = 0; q < 2; ++q) {
        int idx = q * 256 + tid;
        int r = idx >> 3, c = (idx & 7) * 8;
        *(uint4v*)&tile[r][c] = *(const uint4v*)&src[(size_t)(k0 + r) * 64 + c];
    }
    __syncthreads();
    for (int q = 0; q < 2; ++q) {
        int idx = q * 256 + tid;
        int d = idx >> 3, c = (idx & 7) * 8;
        bf16x8 v;
        for (int j = 0; j < 8; ++j) v[j] = tile[c + j][d];
        *(bf16x8*)&dst[(size_t)d * 2048 + k0 + c] = v;
    }
}

// --- GEMM: C[4096x768] = (A @ Bt^T + bias) * scale.  A is bf16 always.
//     MODE 0: C bf16 (proj);  MODE 1: C fp32 (out)
//     R5: XCD-affine block remap. Loop = R7-proven __syncthreads two-phase. ---
struct GArg { const bf16* A; const bf16* Bt; const float* bias; void* C; float scale; };

template<int MODE>
__global__ __launch_bounds__(256) void gemm_bt_bias(GArg g0, GArg g1, GArg g2) {
    const int flat = blockIdx.x + 6 * blockIdx.y + 192 * blockIdx.z;
    const int xcd = flat & 7;
    const int idx = flat >> 3;          // z=3: 0..71, z=1: 0..23
    const int mat = idx / 24;
    const int rem = idx % 24;
    const int rloc = rem / 6, colb = rem % 6;
    GArg ga = mat == 0 ? g0 : mat == 1 ? g1 : g2;
    const int K = 768, N = 768;
    __shared__ bf16 As[2][128][64];
    __shared__ bf16 Bs[2][128][64];
    const int tid = threadIdx.x;
    const int lane = tid & 63, wave = tid >> 6;
    const int l15 = lane & 15, lg = lane >> 4;
    const int r0 = (xcd * 4 + rloc) * 128, c0 = colb * 128;
    const int wr = (wave >> 1) * 64, wc = (wave & 1) * 64;
    f32x4 acc[4][4] = {};

    const int grow = wave * 8 + (lane >> 3);
    const int gcol = 8 * ((lane & 7) ^ (lane >> 3));

    auto stage = [&](int kt, int buf) {
        for (int i = 0; i < 4; ++i)
            gll16(&ga.A[(size_t)(r0 + i * 32 + grow) * K + kt + gcol], &As[buf][i * 32 + wave * 8][0]);
        for (int i = 0; i < 4; ++i)
            gll16(&ga.Bt[(size_t)(c0 + i * 32 + grow) * K + kt + gcol], &Bs[buf][i * 32 + wave * 8][0]);
    };

    stage(0, 0);
    __syncthreads();

    for (int c = 0; c < 12; ++c) {
        const int buf = c & 1;
        if (c < 11) stage((c + 1) * 64, buf ^ 1);   // fire-and-forget, drained at barrier
        for (int kk = 0; kk < 2; ++kk) {
            bf16x8 af[4], bfr[4];
            for (int i = 0; i < 4; ++i) {
                int row = wr + i * 16 + l15;
                af[i] = *(const bf16x8*)&As[buf][row][(kk * 32 + lg * 8) ^ ((row & 7) * 8)];
            }
            for (int j = 0; j < 4; ++j) {
                int row = wc + j * 16 + l15;
                bfr[j] = *(const bf16x8*)&Bs[buf][row][(kk * 32 + lg * 8) ^ ((row & 7) * 8)];
            }
            __builtin_amdgcn_s_setprio(1);
            for (int i = 0; i < 4; ++i)
                for (int j = 0; j < 4; ++j)
                    acc[i][j] = MFMA16(af[i], bfr[j], acc[i][j]);
            __builtin_amdgcn_s_setprio(0);
        }
        __syncthreads();
    }
    for (int j = 0; j < 4; ++j) {
        int col = c0 + wc + j * 16 + l15;
        float bv = ga.bias[col];
        for (int i = 0; i < 4; ++i) {
            int row = r0 + wr + i * 16 + lg * 4;
            for (int r = 0; r < 4; ++r) {
                float val = (acc[i][j][r] + bv) * ga.scale;
                if constexpr (MODE == 0)
                    ((bf16*)ga.C)[(size_t)(row + r) * N + col] = (bf16)val;
                else
                    ((float*)ga.C)[(size_t)(row + r) * N + col] = val;
            }
        }
    }
}

// ------- attention v13: R7-proven loop structure (vmcnt(0) + one barrier) -------
// Block = 4 waves over 64 q-rows. Wave (wq=w>>1, p=w&1): q rows t0+wq*32..+31,
// k-half p of each 64-chunk. Swapped QK: S-regs q=lane&31, k=(r&3)+8*(r>>2)+4*hi.
// bid mapping: xcd = bid&7 keeps K/V L2-local; constant-sum bx permutations
// across slots; s_sleep slot stagger (anti-convoy); hoisted LDS offsets.
__global__ __launch_bounds__(256, 3) void attn_kernel(
    const bf16* __restrict__ Qp, const bf16* __restrict__ Kp,
    const bf16* __restrict__ Vtg, bf16* __restrict__ Ob)
{
    const int bid = blockIdx.x;
    const int xcd = bid & 7;
    const int idx = bid >> 3;            // 0..95
    const int t = idx & 31, s = idx >> 5;
    const int bx = (s == 0) ? (31 - t)
                 : (s == 1) ? ((15 - t) & 31)
                 : (((t << 1) & 31) | (t >> 4));
    const int g = xcd * 3 + s;
    const int t0 = bx * 64;
    const int tid = threadIdx.x, lane = tid & 63, w = tid >> 6;
    const int wq = w >> 1, p = w & 1;
    const int l31 = lane & 31, hi = lane >> 5;

    // anti-convoy stagger: co-resident slots offset ~512*s cycles
    if (s == 1) __builtin_amdgcn_s_sleep(8);
    else if (s == 2) __builtin_amdgcn_s_sleep(16);

    __shared__ __align__(16) char smem[32768];
    bf16* KsE = (bf16*)smem;                 // [2][64][64] d-swizzled
    bf16* VsE = (bf16*)(smem + 16384);       // [2][64][64] V^T, k-swizzled

    const bf16* Qg = Qp + (size_t)g * 131072;
    const bf16* Kg = Kp + (size_t)g * 131072;
    const bf16* Vg = Vtg + (size_t)g * 131072;   // [64][2048]
    bf16* Og = Ob + (size_t)g * 131072;

    // Q B-frags in registers: col=q=l31, k-dim d = m*16 + hi*8 + j
    const int qrow = t0 + wq * 32 + l31;
    bf16x8 qB[4];
    for (int m = 0; m < 4; ++m)
        qB[m] = *(const bf16x8*)&Qg[(size_t)qrow * 64 + m * 16 + hi * 8];

    // staging: wave stages 16 rows (2 gll of 8 rows), pre-swizzled source col
    const int srow = w * 16 + (lane >> 3);
    const int scol = 8 * ((lane & 7) ^ (lane >> 3));
    auto stageK = [&](int ch, int b2) {
        const bf16* src = &Kg[(size_t)(ch * 64 + srow) * 64 + scol];
        bf16* dst = KsE + b2 * 4096 + w * 16 * 64;
        gll16(src, dst);
        gll16(src + 8 * 64, dst + 8 * 64);
    };
    auto stageV = [&](int ch, int b2) {
        const bf16* src = &Vg[(size_t)srow * 2048 + ch * 64 + scol];
        bf16* dst = VsE + b2 * 4096 + w * 16 * 64;
        gll16(src, dst);
        gll16(src + 8 * 2048, dst + 8 * 64);
    };

    stageK(0, 0);
    stageV(0, 0);

    f32x16 oacc0 = {}, oacc1 = {};
    float dsum = 0.f;
    const int qmax = t0 + wq * 32 + 31;                 // wave's q range top
    const int qmin = t0 + wq * 32;
    const int kofs = p * 32;                            // wave's k-half offset
    const int swz = (l31 & 7) * 8;

    // hoisted per-lane LDS element offsets (loop-invariant; buffer = +4096)
    int koff[4], voff0[2], voff1[2];
    for (int m = 0; m < 4; ++m)
        koff[m] = (kofs + l31) * 64 + ((m * 16 + hi * 8) ^ swz);
    for (int kt = 0; kt < 2; ++kt) {
        const int col = (kofs + kt * 16 + hi * 8) ^ swz;
        voff0[kt] = l31 * 64 + col;
        voff1[kt] = (32 + l31) * 64 + col;
    }

    for (int c = 0; c < 32; ++c) {
        const int boff = (c & 1) * 4096;
        asm volatile("s_waitcnt vmcnt(0)" ::: "memory");
        __builtin_amdgcn_s_barrier();
        __builtin_amdgcn_sched_barrier(0);
        if (c < 31) {
            stageK(c + 1, (c & 1) ^ 1);
            if (c + 1 <= bx) stageV(c + 1, (c & 1) ^ 1);
        }
        __builtin_amdgcn_sched_barrier(0);

        const int kc = c * 64;
        const bool activ = (kc + kofs <= qmax);         // wave-uniform
        const bool fullc = (kc + kofs + 31 <= qmin);    // wave-uniform

        // ---- QK^T: A = K rows (wave's 32-k half), B = Q regs
        f32x16 s2 = {};
        __builtin_amdgcn_s_setprio(1);
        for (int m = 0; m < 4; ++m) {
            bf16x8 kf = *(const bf16x8*)&KsE[boff + koff[m]];
            s2 = MFMA32(kf, qB[m], s2);
        }
        __builtin_amdgcn_s_setprio(0);

        // ---- exp2 (Q pre-scaled by log2e/8) + denominator (UNmasked, tree sum)
        float e[16];
        for (int r = 0; r < 16; ++r) e[r] = __builtin_exp2f(s2[r]);
        {
            float p01 = e[0] + e[1],  p23 = e[2] + e[3];
            float p45 = e[4] + e[5],  p67 = e[6] + e[7];
            float p89 = e[8] + e[9],  pab = e[10] + e[11];
            float pcd = e[12] + e[13], pef = e[14] + e[15];
            float q0 = p01 + p23, q1 = p45 + p67, q2 = p89 + pab, q3 = pcd + pef;
            dsum += (q0 + q1) + (q2 + q3);
        }

        if (activ) {
            if (!fullc) {   // diagonal: tril AFTER softmax
                for (int r = 0; r < 16; ++r) {
                    int kg = kc + kofs + (r & 3) + 8 * (r >> 2) + 4 * hi;
                    if (kg > qrow) e[r] = 0.f;
                }
            }
            // ---- pack P to bf16 + permlane32_swap -> 2 PV A-frags, no LDS
            bf16x8 pf[2];
            {
                unsigned a0 = pk_bf16(e[0], e[1]), a1 = pk_bf16(e[2], e[3]);
                unsigned b0 = pk_bf16(e[4], e[5]), b1 = pk_bf16(e[6], e[7]);
                plane32swap(a0, b0); plane32swap(a1, b1);
                pf[0] = frag_words(a0, a1, b0, b1);
                a0 = pk_bf16(e[8], e[9]);   a1 = pk_bf16(e[10], e[11]);
                b0 = pk_bf16(e[12], e[13]); b1 = pk_bf16(e[14], e[15]);
                plane32swap(a0, b0); plane32swap(a1, b1);
                pf[1] = frag_words(a0, a1, b0, b1);
            }
            // ---- PV: A = P frags, B = V^T tile (col d, row k)
            __builtin_amdgcn_s_setprio(1);
            for (int kt = 0; kt < 2; ++kt) {
                bf16x8 v0 = *(const bf16x8*)&VsE[boff + voff0[kt]];
                bf16x8 v1 = *(const bf16x8*)&VsE[boff + voff1[kt]];
                oacc0 = MFMA32(pf[kt], v0, oacc0);
                oacc1 = MFMA32(pf[kt], v1, oacc1);
            }
            __builtin_amdgcn_s_setprio(0);
        }
    }

    // ---- wave-internal k reduce: lane & lane^32 hold complementary k for q=l31
    dsum += __shfl_xor(dsum, 32);

    // ---- cross-pair reduce via LDS overlay (Ks/Vs regions dead after loop)
    __syncthreads();
    float* Ored = (float*)smem;                 // [pair][q 0-31][d 0-63] = 2 x 8KB
    float* dred = (float*)(smem + 16384);       // [wave][q 0-31] = 512 B
    if (l31 == lane) dred[w * 32 + l31] = dsum; // lanes 0-31 only
    if (p == 1) {
        float* Op = Ored + wq * 2048;
        for (int r = 0; r < 16; ++r) {
            const int qoff = (r & 3) + 8 * (r >> 2) + 4 * hi;
            Op[qoff * 64 + l31]      = oacc0[r];
            Op[qoff * 64 + 32 + l31] = oacc1[r];
        }
    }
    __syncthreads();
    if (p == 0) {
        const float dtot = dsum + dred[(w + 1) * 32 + l31];
        const float rall = 1.0f / dtot;          // valid for q=l31 at every lane
        const float* Op = Ored + wq * 2048;
        for (int r = 0; r < 16; ++r) {
            const int qoff = (r & 3) + 8 * (r >> 2) + 4 * hi;
            const float inv = __shfl(rall, qoff);
            const size_t row = (size_t)(t0 + wq * 32 + qoff) * 64;
            Og[row + l31]      = (bf16)((oacc0[r] + Op[qoff * 64 + l31])      * inv);
            Og[row + 32 + l31] = (bf16)((oacc1[r] + Op[qoff * 64 + 32 + l31]) * inv);
        }
    }
}

// ---------------- host ----------------
extern "C" void kernel_launch(void* const* d_in, const int* in_sizes, int n_in,
                              void* d_out, int out_size, void* d_ws, size_t ws_size,
                              hipStream_t stream) {
    const float* query = (const float*)d_in[0];
    const float* key_  = (const float*)d_in[1];
    const float* value = (const float*)d_in[2];
    const float* Wq = (const float*)d_in[3];
    const float* bq = (const float*)d_in[4];
    const float* Wk = (const float*)d_in[5];
    const float* bk = (const float*)d_in[6];
    const float* Wv = (const float*)d_in[7];
    const float* bv = (const float*)d_in[8];
    const float* Wo = (const float*)d_in[9];
    const float* bo = (const float*)d_in[10];
    float* out = (float*)d_out;

    const size_t MN = (size_t)4096 * 768;
    const size_t WW = (size_t)768 * 768;
    bf16* Qp  = (bf16*)d_ws;
    bf16* Kp  = Qp + MN;
    bf16* Vp  = Kp + MN;     // V projection, standard [4096][768] layout
    bf16* Obf = Vp + MN;
    bf16* Vtg = Obf + MN;    // V^T slabs, written by vtrans
    bf16* WtQ = Vtg + MN;
    bf16* WtK = WtQ + WW;
    bf16* WtV = WtK + WW;
    bf16* WtO = WtV + WW;
    bf16* Vb  = WtO + WW;    // +1 MN slab
    // bf16 activation inputs alias slabs that are dead until after gemm<0>:
    bf16* Qb  = Obf;         // Obf written only by attn (after gemm<0> reads Qb)
    bf16* Kb  = Vtg;         // Vtg written by vtrans (after gemm<0> reads Kb)

    prelude<<<dim3(5184), 256, 0, stream>>>(
        query, key_, value, Qb, Kb, Vb,
        TArg{Wq, WtQ}, TArg{Wk, WtK}, TArg{Wv, WtV}, TArg{Wo, WtO});

    // fold log2(e)/sqrt(HD) into Q so attention uses native exp2
    gemm_bt_bias<0><<<dim3(6, 32, 3), 256, 0, stream>>>(
        GArg{Qb, WtQ, bq, Qp, 0.18033688f},
        GArg{Kb, WtK, bk, Kp, 1.0f},
        GArg{Vb, WtV, bv, Vp, 1.0f});

    vtrans<<<dim3(32, 24), 256, 0, stream>>>(Vp, Vtg);

    attn_kernel<<<dim3(768), 256, 0, stream>>>(Qp, Kp, Vtg, Obf);

    gemm_bt_bias<1><<<dim3(6, 32, 1), 256, 0, stream>>>(
        GArg{Obf, WtO, bo, out, 1.0f},
        GArg{Obf, WtO, bo, out, 1.0f},
        GArg{Obf, WtO, bo, out, 1.0f});
}

// Round 12
// 105.368 us; speedup vs baseline: 1.1280x; 1.0118x over previous
//
#include <hip/hip_runtime.h>
#include <hip/hip_bf16.h>

// MultiHeadAttentionLegacy: B=2, S=2048, E=768, H=12, HD=64, G=B*H=24
// Inputs fp32, output fp32; internal bf16 MFMA pipeline.
// Legacy reshape = pure flat re-chunk: [4096][768] buffer == 24 slabs [2048][64].
// Softmax denominator over FULL row; tril mask applied AFTER softmax.
// Q projection pre-scaled by log2(e)/sqrt(64) so attention uses exp2 directly.
//
// R1: pre-convert q/k/v fp32->bf16 (gll staging for both GEMM operands).
// R2 (FAILED): deeper attn LDS pipeline -> worse. Not latency-bound.
// R3 (FAILED): direct per-lane L2 reads -> 2x worse. LDS staging is right.
// R4 (FAILED): fewer rounds via tail-pairing -> slightly worse.
// R5 (WIN): constant-sum bx triplets balance per-CU PV load; XCD-affine GEMM.
// R6 (small WIN): launch_bounds(256,3) + hoisted LDS offsets.
// R7 (small WIN): s_sleep slot stagger (anti-convoy).
// R8/R9 (FAILED): vt-fused V epilogue had wrong legacy mapping (bisect: the
//   counted-vmcnt loops were NOT the bug -- absmax identical after reverting).
// R10 (passed, SLOW): correct vt mapping = stride-12 2B scatter. Fused-vt dead.
// R11 (WIN): separate vtrans + prelude fusion banked. 106.6us.
// R12: counted-vmcnt GEMM loop as the SOLE change (the untested R8 idea).
//   __syncthreads drained vmcnt(0) every k-step, killing the prefetch; now
//   stage(c+1) is issued first, s_waitcnt vmcnt(8) waits only for stage(c),
//   two raw barriers per iter bracket the LDS lifetime.

typedef __bf16 bf16;
typedef __attribute__((ext_vector_type(4))) __bf16 bf16x4;
typedef __attribute__((ext_vector_type(8))) __bf16 bf16x8;
typedef __attribute__((ext_vector_type(4))) float f32x4;
typedef __attribute__((ext_vector_type(16))) float f32x16;
typedef __attribute__((ext_vector_type(4))) unsigned int uint4v;

#define MFMA16(a,b,c) __builtin_amdgcn_mfma_f32_16x16x32_bf16((a),(b),(c),0,0,0)
#define MFMA32(a,b,c) __builtin_amdgcn_mfma_f32_32x32x16_bf16((a),(b),(c),0,0,0)

typedef const __attribute__((address_space(1))) unsigned int GU32;
typedef __attribute__((address_space(3))) unsigned int LU32;

__device__ __forceinline__ void gll16(const void* gsrc, void* ldst) {
    __builtin_amdgcn_global_load_lds((GU32*)gsrc, (LU32*)ldst, 16, 0, 0);
}

__device__ __forceinline__ unsigned pk_bf16(float lo, float hi) {
    unsigned r;
    asm("v_cvt_pk_bf16_f32 %0, %1, %2" : "=v"(r) : "v"(lo), "v"(hi));
    return r;
}

// v_permlane32_swap_b32: a.hi32lanes <-> b.lo32lanes
__device__ __forceinline__ void plane32swap(unsigned &a, unsigned &b) {
    asm("v_permlane32_swap_b32 %0, %1" : "+v"(a), "+v"(b));
}

__device__ __forceinline__ bf16x8 frag_words(unsigned w0, unsigned w1, unsigned w2, unsigned w3) {
    union { unsigned u[4]; bf16x8 v; } f;
    f.u[0] = w0; f.u[1] = w1; f.u[2] = w2; f.u[3] = w3;
    return f.v;
}

// ------- fused prelude: cvt (blocks 0..4607) + weight transpose (4608..5183) -------
struct TArg { const float* in; bf16* out; };

__global__ __launch_bounds__(256) void prelude(
    const float* __restrict__ q, const float* __restrict__ k, const float* __restrict__ v,
    bf16* __restrict__ Qb, bf16* __restrict__ Kb, bf16* __restrict__ Vb,
    TArg a0, TArg a1, TArg a2, TArg a3)
{
    __shared__ bf16 tile[64][72];
    const int b = blockIdx.x;
    const int tid = threadIdx.x;
    if (b < 4608) {
        const int m = b / 1536, xx = b % 1536;
        const float* src = m == 0 ? q : m == 1 ? k : v;
        bf16* dst = m == 0 ? Qb : m == 1 ? Kb : Vb;
        const size_t base = (size_t)xx * 2048 + (size_t)tid * 8;
        f32x4 lo = *(const f32x4*)&src[base];
        f32x4 hi = *(const f32x4*)&src[base + 4];
        bf16x8 o;
        for (int j = 0; j < 4; ++j) { o[j] = (bf16)lo[j]; o[4 + j] = (bf16)hi[j]; }
        *(bf16x8*)&dst[base] = o;
    } else {
        const int bb = b - 4608;                // 0..575
        const int wz = bb / 144, bxy = bb % 144;
        TArg ta = wz == 0 ? a0 : wz == 1 ? a1 : wz == 2 ? a2 : a3;
        const int bx = bxy % 12, by = bxy / 12;
        const int k0 = by * 64, n0 = bx * 64;
        for (int qq = 0; qq < 2; ++qq) {
            int idx = qq * 256 + tid;
            int i = idx >> 3, j0 = (idx & 7) * 8;
            const float* src = &ta.in[(size_t)(k0 + i) * 768 + n0 + j0];
            f32x4 lo = *(const f32x4*)&src[0];
            f32x4 hi = *(const f32x4*)&src[4];
            bf16x8 vv;
            for (int j = 0; j < 4; ++j) { vv[j] = (bf16)lo[j]; vv[4 + j] = (bf16)hi[j]; }
            *(bf16x8*)&tile[i][j0] = vv;
        }
        __syncthreads();
        for (int qq = 0; qq < 2; ++qq) {
            int idx = qq * 256 + tid;
            int n = idx >> 3, j0 = (idx & 7) * 8;
            bf16x8 vv;
            for (int jj = 0; jj < 8; ++jj) vv[jj] = tile[j0 + jj][n];
            *(bf16x8*)&ta.out[(size_t)(n0 + n) * 768 + k0 + j0] = vv;
        }
    }
}

// ------- V slab transpose: Vt[g][d][k] = Vp_flat[g*131072 + k*64 + d] -------
__global__ __launch_bounds__(256) void vtrans(const bf16* __restrict__ Vp, bf16* __restrict__ Vt) {
    __shared__ bf16 tile[64][72];
    const int g = blockIdx.y;
    const int k0 = blockIdx.x * 64;
    const bf16* src = Vp + (size_t)g * 131072;
    bf16* dst = Vt + (size_t)g * 131072;
    const int tid = threadIdx.x;
    for (int q = 0; q < 2; ++q) {
        int idx = q * 256 + tid;
        int r = idx >> 3, c = (idx & 7) * 8;
        *(uint4v*)&tile[r][c] = *(const uint4v*)&src[(size_t)(k0 + r) * 64 + c];
    }
    __syncthreads();
    for (int q = 0; q < 2; ++q) {
        int idx = q * 256 + tid;
        int d = idx >> 3, c = (idx & 7) * 8;
        bf16x8 v;
        for (int j = 0; j < 8; ++j) v[j] = tile[c + j][d];
        *(bf16x8*)&dst[(size_t)d * 2048 + k0 + c] = v;
    }
}

// --- GEMM: C[4096x768] = (A @ Bt^T + bias) * scale.  A is bf16 always.
//     MODE 0: C bf16 (proj);  MODE 1: C fp32 (out)
//     R5: XCD-affine block remap. R12: counted vmcnt(8) prefetch loop --
//     stage(c+1) stays in flight across the compute phase; only stage(c)
//     is awaited. Two raw s_barriers bracket each buffer's read lifetime. ---
struct GArg { const bf16* A; const bf16* Bt; const float* bias; void* C; float scale; };

template<int MODE>
__global__ __launch_bounds__(256) void gemm_bt_bias(GArg g0, GArg g1, GArg g2) {
    const int flat = blockIdx.x + 6 * blockIdx.y + 192 * blockIdx.z;
    const int xcd = flat & 7;
    const int idx = flat >> 3;          // z=3: 0..71, z=1: 0..23
    const int mat = idx / 24;
    const int rem = idx % 24;
    const int rloc = rem / 6, colb = rem % 6;
    GArg ga = mat == 0 ? g0 : mat == 1 ? g1 : g2;
    const int K = 768, N = 768;
    __shared__ bf16 As[2][128][64];
    __shared__ bf16 Bs[2][128][64];
    const int tid = threadIdx.x;
    const int lane = tid & 63, wave = tid >> 6;
    const int l15 = lane & 15, lg = lane >> 4;
    const int r0 = (xcd * 4 + rloc) * 128, c0 = colb * 128;
    const int wr = (wave >> 1) * 64, wc = (wave & 1) * 64;
    f32x4 acc[4][4] = {};

    const int grow = wave * 8 + (lane >> 3);
    const int gcol = 8 * ((lane & 7) ^ (lane >> 3));

    auto stage = [&](int kt, int buf) {
        for (int i = 0; i < 4; ++i)
            gll16(&ga.A[(size_t)(r0 + i * 32 + grow) * K + kt + gcol], &As[buf][i * 32 + wave * 8][0]);
        for (int i = 0; i < 4; ++i)
            gll16(&ga.Bt[(size_t)(c0 + i * 32 + grow) * K + kt + gcol], &Bs[buf][i * 32 + wave * 8][0]);
    };

    stage(0, 0);                                  // 8 glls in flight

    for (int c = 0; c < 12; ++c) {
        const int buf = c & 1;
        // issue prefetch FIRST (prev end-barrier guarantees buf^1 is free),
        // then wait only for stage(c)'s 8 loads (this wave's oldest 8).
        if (c < 11) {
            stage((c + 1) * 64, buf ^ 1);
            asm volatile("s_waitcnt vmcnt(8)" ::: "memory");
        } else {
            asm volatile("s_waitcnt vmcnt(0)" ::: "memory");
        }
        __builtin_amdgcn_s_barrier();             // all waves' stage(c) landed
        __builtin_amdgcn_sched_barrier(0);
        for (int kk = 0; kk < 2; ++kk) {
            bf16x8 af[4], bfr[4];
            for (int i = 0; i < 4; ++i) {
                int row = wr + i * 16 + l15;
                af[i] = *(const bf16x8*)&As[buf][row][(kk * 32 + lg * 8) ^ ((row & 7) * 8)];
            }
            for (int j = 0; j < 4; ++j) {
                int row = wc + j * 16 + l15;
                bfr[j] = *(const bf16x8*)&Bs[buf][row][(kk * 32 + lg * 8) ^ ((row & 7) * 8)];
            }
            __builtin_amdgcn_s_setprio(1);
            for (int i = 0; i < 4; ++i)
                for (int j = 0; j < 4; ++j)
                    acc[i][j] = MFMA16(af[i], bfr[j], acc[i][j]);
            __builtin_amdgcn_s_setprio(0);
        }
        __builtin_amdgcn_sched_barrier(0);
        __builtin_amdgcn_s_barrier();             // all waves done reading buf
    }
    for (int j = 0; j < 4; ++j) {
        int col = c0 + wc + j * 16 + l15;
        float bv = ga.bias[col];
        for (int i = 0; i < 4; ++i) {
            int row = r0 + wr + i * 16 + lg * 4;
            for (int r = 0; r < 4; ++r) {
                float val = (acc[i][j][r] + bv) * ga.scale;
                if constexpr (MODE == 0)
                    ((bf16*)ga.C)[(size_t)(row + r) * N + col] = (bf16)val;
                else
                    ((float*)ga.C)[(size_t)(row + r) * N + col] = val;
            }
        }
    }
}

// ------- attention v13: R7-proven loop structure (vmcnt(0) + one barrier) -------
// Block = 4 waves over 64 q-rows. Wave (wq=w>>1, p=w&1): q rows t0+wq*32..+31,
// k-half p of each 64-chunk. Swapped QK: S-regs q=lane&31, k=(r&3)+8*(r>>2)+4*hi.
// bid mapping: xcd = bid&7 keeps K/V L2-local; constant-sum bx permutations
// across slots; s_sleep slot stagger (anti-convoy); hoisted LDS offsets.
__global__ __launch_bounds__(256, 3) void attn_kernel(
    const bf16* __restrict__ Qp, const bf16* __restrict__ Kp,
    const bf16* __restrict__ Vtg, bf16* __restrict__ Ob)
{
    const int bid = blockIdx.x;
    const int xcd = bid & 7;
    const int idx = bid >> 3;            // 0..95
    const int t = idx & 31, s = idx >> 5;
    const int bx = (s == 0) ? (31 - t)
                 : (s == 1) ? ((15 - t) & 31)
                 : (((t << 1) & 31) | (t >> 4));
    const int g = xcd * 3 + s;
    const int t0 = bx * 64;
    const int tid = threadIdx.x, lane = tid & 63, w = tid >> 6;
    const int wq = w >> 1, p = w & 1;
    const int l31 = lane & 31, hi = lane >> 5;

    // anti-convoy stagger: co-resident slots offset ~512*s cycles
    if (s == 1) __builtin_amdgcn_s_sleep(8);
    else if (s == 2) __builtin_amdgcn_s_sleep(16);

    __shared__ __align__(16) char smem[32768];
    bf16* KsE = (bf16*)smem;                 // [2][64][64] d-swizzled
    bf16* VsE = (bf16*)(smem + 16384);       // [2][64][64] V^T, k-swizzled

    const bf16* Qg = Qp + (size_t)g * 131072;
    const bf16* Kg = Kp + (size_t)g * 131072;
    const bf16* Vg = Vtg + (size_t)g * 131072;   // [64][2048]
    bf16* Og = Ob + (size_t)g * 131072;

    // Q B-frags in registers: col=q=l31, k-dim d = m*16 + hi*8 + j
    const int qrow = t0 + wq * 32 + l31;
    bf16x8 qB[4];
    for (int m = 0; m < 4; ++m)
        qB[m] = *(const bf16x8*)&Qg[(size_t)qrow * 64 + m * 16 + hi * 8];

    // staging: wave stages 16 rows (2 gll of 8 rows), pre-swizzled source col
    const int srow = w * 16 + (lane >> 3);
    const int scol = 8 * ((lane & 7) ^ (lane >> 3));
    auto stageK = [&](int ch, int b2) {
        const bf16* src = &Kg[(size_t)(ch * 64 + srow) * 64 + scol];
        bf16* dst = KsE + b2 * 4096 + w * 16 * 64;
        gll16(src, dst);
        gll16(src + 8 * 64, dst + 8 * 64);
    };
    auto stageV = [&](int ch, int b2) {
        const bf16* src = &Vg[(size_t)srow * 2048 + ch * 64 + scol];
        bf16* dst = VsE + b2 * 4096 + w * 16 * 64;
        gll16(src, dst);
        gll16(src + 8 * 2048, dst + 8 * 64);
    };

    stageK(0, 0);
    stageV(0, 0);

    f32x16 oacc0 = {}, oacc1 = {};
    float dsum = 0.f;
    const int qmax = t0 + wq * 32 + 31;                 // wave's q range top
    const int qmin = t0 + wq * 32;
    const int kofs = p * 32;                            // wave's k-half offset
    const int swz = (l31 & 7) * 8;

    // hoisted per-lane LDS element offsets (loop-invariant; buffer = +4096)
    int koff[4], voff0[2], voff1[2];
    for (int m = 0; m < 4; ++m)
        koff[m] = (kofs + l31) * 64 + ((m * 16 + hi * 8) ^ swz);
    for (int kt = 0; kt < 2; ++kt) {
        const int col = (kofs + kt * 16 + hi * 8) ^ swz;
        voff0[kt] = l31 * 64 + col;
        voff1[kt] = (32 + l31) * 64 + col;
    }

    for (int c = 0; c < 32; ++c) {
        const int boff = (c & 1) * 4096;
        asm volatile("s_waitcnt vmcnt(0)" ::: "memory");
        __builtin_amdgcn_s_barrier();
        __builtin_amdgcn_sched_barrier(0);
        if (c < 31) {
            stageK(c + 1, (c & 1) ^ 1);
            if (c + 1 <= bx) stageV(c + 1, (c & 1) ^ 1);
        }
        __builtin_amdgcn_sched_barrier(0);

        const int kc = c * 64;
        const bool activ = (kc + kofs <= qmax);         // wave-uniform
        const bool fullc = (kc + kofs + 31 <= qmin);    // wave-uniform

        // ---- QK^T: A = K rows (wave's 32-k half), B = Q regs
        f32x16 s2 = {};
        __builtin_amdgcn_s_setprio(1);
        for (int m = 0; m < 4; ++m) {
            bf16x8 kf = *(const bf16x8*)&KsE[boff + koff[m]];
            s2 = MFMA32(kf, qB[m], s2);
        }
        __builtin_amdgcn_s_setprio(0);

        // ---- exp2 (Q pre-scaled by log2e/8) + denominator (UNmasked, tree sum)
        float e[16];
        for (int r = 0; r < 16; ++r) e[r] = __builtin_exp2f(s2[r]);
        {
            float p01 = e[0] + e[1],  p23 = e[2] + e[3];
            float p45 = e[4] + e[5],  p67 = e[6] + e[7];
            float p89 = e[8] + e[9],  pab = e[10] + e[11];
            float pcd = e[12] + e[13], pef = e[14] + e[15];
            float q0 = p01 + p23, q1 = p45 + p67, q2 = p89 + pab, q3 = pcd + pef;
            dsum += (q0 + q1) + (q2 + q3);
        }

        if (activ) {
            if (!fullc) {   // diagonal: tril AFTER softmax
                for (int r = 0; r < 16; ++r) {
                    int kg = kc + kofs + (r & 3) + 8 * (r >> 2) + 4 * hi;
                    if (kg > qrow) e[r] = 0.f;
                }
            }
            // ---- pack P to bf16 + permlane32_swap -> 2 PV A-frags, no LDS
            bf16x8 pf[2];
            {
                unsigned a0 = pk_bf16(e[0], e[1]), a1 = pk_bf16(e[2], e[3]);
                unsigned b0 = pk_bf16(e[4], e[5]), b1 = pk_bf16(e[6], e[7]);
                plane32swap(a0, b0); plane32swap(a1, b1);
                pf[0] = frag_words(a0, a1, b0, b1);
                a0 = pk_bf16(e[8], e[9]);   a1 = pk_bf16(e[10], e[11]);
                b0 = pk_bf16(e[12], e[13]); b1 = pk_bf16(e[14], e[15]);
                plane32swap(a0, b0); plane32swap(a1, b1);
                pf[1] = frag_words(a0, a1, b0, b1);
            }
            // ---- PV: A = P frags, B = V^T tile (col d, row k)
            __builtin_amdgcn_s_setprio(1);
            for (int kt = 0; kt < 2; ++kt) {
                bf16x8 v0 = *(const bf16x8*)&VsE[boff + voff0[kt]];
                bf16x8 v1 = *(const bf16x8*)&VsE[boff + voff1[kt]];
                oacc0 = MFMA32(pf[kt], v0, oacc0);
                oacc1 = MFMA32(pf[kt], v1, oacc1);
            }
            __builtin_amdgcn_s_setprio(0);
        }
    }

    // ---- wave-internal k reduce: lane & lane^32 hold complementary k for q=l31
    dsum += __shfl_xor(dsum, 32);

    // ---- cross-pair reduce via LDS overlay (Ks/Vs regions dead after loop)
    __syncthreads();
    float* Ored = (float*)smem;                 // [pair][q 0-31][d 0-63] = 2 x 8KB
    float* dred = (float*)(smem + 16384);       // [wave][q 0-31] = 512 B
    if (l31 == lane) dred[w * 32 + l31] = dsum; // lanes 0-31 only
    if (p == 1) {
        float* Op = Ored + wq * 2048;
        for (int r = 0; r < 16; ++r) {
            const int qoff = (r & 3) + 8 * (r >> 2) + 4 * hi;
            Op[qoff * 64 + l31]      = oacc0[r];
            Op[qoff * 64 + 32 + l31] = oacc1[r];
        }
    }
    __syncthreads();
    if (p == 0) {
        const float dtot = dsum + dred[(w + 1) * 32 + l31];
        const float rall = 1.0f / dtot;          // valid for q=l31 at every lane
        const float* Op = Ored + wq * 2048;
        for (int r = 0; r < 16; ++r) {
            const int qoff = (r & 3) + 8 * (r >> 2) + 4 * hi;
            const float inv = __shfl(rall, qoff);
            const size_t row = (size_t)(t0 + wq * 32 + qoff) * 64;
            Og[row + l31]      = (bf16)((oacc0[r] + Op[qoff * 64 + l31])      * inv);
            Og[row + 32 + l31] = (bf16)((oacc1[r] + Op[qoff * 64 + 32 + l31]) * inv);
        }
    }
}

// ---------------- host ----------------
extern "C" void kernel_launch(void* const* d_in, const int* in_sizes, int n_in,
                              void* d_out, int out_size, void* d_ws, size_t ws_size,
                              hipStream_t stream) {
    const float* query = (const float*)d_in[0];
    const float* key_  = (const float*)d_in[1];
    const float* value = (const float*)d_in[2];
    const float* Wq = (const float*)d_in[3];
    const float* bq = (const float*)d_in[4];
    const float* Wk = (const float*)d_in[5];
    const float* bk = (const float*)d_in[6];
    const float* Wv = (const float*)d_in[7];
    const float* bv = (const float*)d_in[8];
    const float* Wo = (const float*)d_in[9];
    const float* bo = (const float*)d_in[10];
    float* out = (float*)d_out;

    const size_t MN = (size_t)4096 * 768;
    const size_t WW = (size_t)768 * 768;
    bf16* Qp  = (bf16*)d_ws;
    bf16* Kp  = Qp + MN;
    bf16* Vp  = Kp + MN;     // V projection, standard [4096][768] layout
    bf16* Obf = Vp + MN;
    bf16* Vtg = Obf + MN;    // V^T slabs, written by vtrans
    bf16* WtQ = Vtg + MN;
    bf16* WtK = WtQ + WW;
    bf16* WtV = WtK + WW;
    bf16* WtO = WtV + WW;
    bf16* Vb  = WtO + WW;    // +1 MN slab
    // bf16 activation inputs alias slabs that are dead until after gemm<0>:
    bf16* Qb  = Obf;         // Obf written only by attn (after gemm<0> reads Qb)
    bf16* Kb  = Vtg;         // Vtg written by vtrans (after gemm<0> reads Kb)

    prelude<<<dim3(5184), 256, 0, stream>>>(
        query, key_, value, Qb, Kb, Vb,
        TArg{Wq, WtQ}, TArg{Wk, WtK}, TArg{Wv, WtV}, TArg{Wo, WtO});

    // fold log2(e)/sqrt(HD) into Q so attention uses native exp2
    gemm_bt_bias<0><<<dim3(6, 32, 3), 256, 0, stream>>>(
        GArg{Qb, WtQ, bq, Qp, 0.18033688f},
        GArg{Kb, WtK, bk, Kp, 1.0f},
        GArg{Vb, WtV, bv, Vp, 1.0f});

    vtrans<<<dim3(32, 24), 256, 0, stream>>>(Vp, Vtg);

    attn_kernel<<<dim3(768), 256, 0, stream>>>(Qp, Kp, Vtg, Obf);

    gemm_bt_bias<1><<<dim3(6, 32, 1), 256, 0, stream>>>(
        GArg{Obf, WtO, bo, out, 1.0f},
        GArg{Obf, WtO, bo, out, 1.0f},
        GArg{Obf, WtO, bo, out, 1.0f});
}

// Round 13
// 100.069 us; speedup vs baseline: 1.1877x; 1.0530x over previous
//
#include <hip/hip_runtime.h>
#include <hip/hip_bf16.h>

// MultiHeadAttentionLegacy: B=2, S=2048, E=768, H=12, HD=64, G=B*H=24
// Inputs fp32, output fp32; internal bf16 MFMA pipeline.
// Legacy reshape = pure flat re-chunk: [4096][768] buffer == 24 slabs [2048][64].
// Softmax denominator over FULL row; tril mask applied AFTER softmax.
// Q projection pre-scaled by log2(e)/sqrt(64) so attention uses exp2 directly.
//
// R1: pre-convert q/k/v fp32->bf16 (gll staging for both GEMM operands).
// R2 (FAILED): deeper attn LDS pipeline -> worse. Not latency-bound.
// R3 (FAILED): direct per-lane L2 reads -> 2x worse. LDS staging is right.
// R4 (FAILED): fewer rounds via tail-pairing -> slightly worse.
// R5 (WIN): constant-sum bx triplets balance per-CU PV load; XCD-affine GEMM.
// R6 (small WIN): launch_bounds(256,3) + hoisted LDS offsets.
// R7 (small WIN): s_sleep slot stagger (anti-convoy).
// R8/R9 (FAILED): vt-fused V epilogue had wrong legacy mapping.
// R10 (passed, SLOW): correct vt mapping = stride-12 2B scatter. Fused-vt dead.
// R11 (WIN): separate vtrans + prelude fusion banked. 106.6us.
// R12 (small WIN): counted-vmcnt GEMM loop. 105.4us. Small gain => drain was
//   not the gemm's main stall.
// R13: GEMM DISPATCH BALANCE. 128x128 tiles gave 576 blocks = 2.25/CU (33%
//   tail: 64 CUs run 3 blocks, 192 run 2) and only 9 waves/CU; gemm<1> was
//   192 blocks = 0.75/CU (quarter of the chip idle). Switch to 64x64 tiles:
//   gemm<0> = 2304 blocks = 9/CU exact, gemm<1> = 768 = 3/CU exact; 32KB LDS
//   -> 5 blocks resident/CU (20 waves) for real latency hiding. Stage/swizzle
//   reuses the proven [64][64] pattern (attn's stageK); loop is R12's
//   counted-vmcnt (4 glls/wave -> vmcnt(4)).

typedef __bf16 bf16;
typedef __attribute__((ext_vector_type(4))) __bf16 bf16x4;
typedef __attribute__((ext_vector_type(8))) __bf16 bf16x8;
typedef __attribute__((ext_vector_type(4))) float f32x4;
typedef __attribute__((ext_vector_type(16))) float f32x16;
typedef __attribute__((ext_vector_type(4))) unsigned int uint4v;

#define MFMA16(a,b,c) __builtin_amdgcn_mfma_f32_16x16x32_bf16((a),(b),(c),0,0,0)
#define MFMA32(a,b,c) __builtin_amdgcn_mfma_f32_32x32x16_bf16((a),(b),(c),0,0,0)

typedef const __attribute__((address_space(1))) unsigned int GU32;
typedef __attribute__((address_space(3))) unsigned int LU32;

__device__ __forceinline__ void gll16(const void* gsrc, void* ldst) {
    __builtin_amdgcn_global_load_lds((GU32*)gsrc, (LU32*)ldst, 16, 0, 0);
}

__device__ __forceinline__ unsigned pk_bf16(float lo, float hi) {
    unsigned r;
    asm("v_cvt_pk_bf16_f32 %0, %1, %2" : "=v"(r) : "v"(lo), "v"(hi));
    return r;
}

// v_permlane32_swap_b32: a.hi32lanes <-> b.lo32lanes
__device__ __forceinline__ void plane32swap(unsigned &a, unsigned &b) {
    asm("v_permlane32_swap_b32 %0, %1" : "+v"(a), "+v"(b));
}

__device__ __forceinline__ bf16x8 frag_words(unsigned w0, unsigned w1, unsigned w2, unsigned w3) {
    union { unsigned u[4]; bf16x8 v; } f;
    f.u[0] = w0; f.u[1] = w1; f.u[2] = w2; f.u[3] = w3;
    return f.v;
}

// ------- fused prelude: cvt (blocks 0..4607) + weight transpose (4608..5183) -------
struct TArg { const float* in; bf16* out; };

__global__ __launch_bounds__(256) void prelude(
    const float* __restrict__ q, const float* __restrict__ k, const float* __restrict__ v,
    bf16* __restrict__ Qb, bf16* __restrict__ Kb, bf16* __restrict__ Vb,
    TArg a0, TArg a1, TArg a2, TArg a3)
{
    __shared__ bf16 tile[64][72];
    const int b = blockIdx.x;
    const int tid = threadIdx.x;
    if (b < 4608) {
        const int m = b / 1536, xx = b % 1536;
        const float* src = m == 0 ? q : m == 1 ? k : v;
        bf16* dst = m == 0 ? Qb : m == 1 ? Kb : Vb;
        const size_t base = (size_t)xx * 2048 + (size_t)tid * 8;
        f32x4 lo = *(const f32x4*)&src[base];
        f32x4 hi = *(const f32x4*)&src[base + 4];
        bf16x8 o;
        for (int j = 0; j < 4; ++j) { o[j] = (bf16)lo[j]; o[4 + j] = (bf16)hi[j]; }
        *(bf16x8*)&dst[base] = o;
    } else {
        const int bb = b - 4608;                // 0..575
        const int wz = bb / 144, bxy = bb % 144;
        TArg ta = wz == 0 ? a0 : wz == 1 ? a1 : wz == 2 ? a2 : a3;
        const int bx = bxy % 12, by = bxy / 12;
        const int k0 = by * 64, n0 = bx * 64;
        for (int qq = 0; qq < 2; ++qq) {
            int idx = qq * 256 + tid;
            int i = idx >> 3, j0 = (idx & 7) * 8;
            const float* src = &ta.in[(size_t)(k0 + i) * 768 + n0 + j0];
            f32x4 lo = *(const f32x4*)&src[0];
            f32x4 hi = *(const f32x4*)&src[4];
            bf16x8 vv;
            for (int j = 0; j < 4; ++j) { vv[j] = (bf16)lo[j]; vv[4 + j] = (bf16)hi[j]; }
            *(bf16x8*)&tile[i][j0] = vv;
        }
        __syncthreads();
        for (int qq = 0; qq < 2; ++qq) {
            int idx = qq * 256 + tid;
            int n = idx >> 3, j0 = (idx & 7) * 8;
            bf16x8 vv;
            for (int jj = 0; jj < 8; ++jj) vv[jj] = tile[j0 + jj][n];
            *(bf16x8*)&ta.out[(size_t)(n0 + n) * 768 + k0 + j0] = vv;
        }
    }
}

// ------- V slab transpose: Vt[g][d][k] = Vp_flat[g*131072 + k*64 + d] -------
__global__ __launch_bounds__(256) void vtrans(const bf16* __restrict__ Vp, bf16* __restrict__ Vt) {
    __shared__ bf16 tile[64][72];
    const int g = blockIdx.y;
    const int k0 = blockIdx.x * 64;
    const bf16* src = Vp + (size_t)g * 131072;
    bf16* dst = Vt + (size_t)g * 131072;
    const int tid = threadIdx.x;
    for (int q = 0; q < 2; ++q) {
        int idx = q * 256 + tid;
        int r = idx >> 3, c = (idx & 7) * 8;
        *(uint4v*)&tile[r][c] = *(const uint4v*)&src[(size_t)(k0 + r) * 64 + c];
    }
    __syncthreads();
    for (int q = 0; q < 2; ++q) {
        int idx = q * 256 + tid;
        int d = idx >> 3, c = (idx & 7) * 8;
        bf16x8 v;
        for (int j = 0; j < 8; ++j) v[j] = tile[c + j][d];
        *(bf16x8*)&dst[(size_t)d * 2048 + k0 + c] = v;
    }
}

// --- GEMM: C[4096x768] = (A @ Bt^T + bias) * scale.  A is bf16 always.
//     MODE 0: C bf16 (proj);  MODE 1: C fp32 (out)
//     R13: 64x64 tiles. MODE0: 2304 blocks = 9/CU exact; MODE1: 768 = 3/CU.
//     XCD-affine: xcd = flat&7 owns 8 row-blocks (512 rows, A-slice 0.8MB +
//     B 1.2MB fits 4MB L2), cols fastest. R12 counted-vmcnt loop (4 gll/wave).
//     4 waves in 2x2 of 32x32; acc[2][2]; 8 MFMA16 per k-step per wave. ---
struct GArg { const bf16* A; const bf16* Bt; const float* bias; void* C; float scale; };

template<int MODE>
__global__ __launch_bounds__(256) void gemm_bt_bias(GArg g0, GArg g1, GArg g2) {
    const int flat = blockIdx.x + 12 * blockIdx.y + 768 * blockIdx.z;
    const int xcd = flat & 7;
    const int idx = flat >> 3;          // z=3: 0..287, z=1: 0..95
    const int mat = idx / 96;
    const int rem = idx % 96;
    const int rloc = rem / 12, colb = rem % 12;
    GArg ga = mat == 0 ? g0 : mat == 1 ? g1 : g2;
    const int K = 768, N = 768;
    __shared__ bf16 As[2][64][64];
    __shared__ bf16 Bs[2][64][64];
    const int tid = threadIdx.x;
    const int lane = tid & 63, wave = tid >> 6;
    const int l15 = lane & 15, lg = lane >> 4;
    const int r0 = (xcd * 8 + rloc) * 64, c0 = colb * 64;
    const int wr = (wave >> 1) * 32, wc = (wave & 1) * 32;
    f32x4 acc[2][2] = {};

    // staging: wave stages 16 rows of A and 16 of B (2 glls each);
    // 8 rows per gll, pre-swizzled source col (same pattern as attn stageK)
    const int grow = lane >> 3;                       // 0..7
    const int gcol = 8 * ((lane & 7) ^ (lane >> 3));  // swizzled col

    auto stage = [&](int kt, int buf) {
        const bf16* srcA = &ga.A[(size_t)(r0 + wave * 16 + grow) * K + kt + gcol];
        gll16(srcA, &As[buf][wave * 16][0]);
        gll16(srcA + 8 * K, &As[buf][wave * 16 + 8][0]);
        const bf16* srcB = &ga.Bt[(size_t)(c0 + wave * 16 + grow) * K + kt + gcol];
        gll16(srcB, &Bs[buf][wave * 16][0]);
        gll16(srcB + 8 * K, &Bs[buf][wave * 16 + 8][0]);
    };

    stage(0, 0);                                  // 4 glls in flight

    for (int c = 0; c < 12; ++c) {
        const int buf = c & 1;
        // issue prefetch FIRST (prev end-barrier guarantees buf^1 is free),
        // then wait only for stage(c)'s 4 loads (this wave's oldest 4).
        if (c < 11) {
            stage((c + 1) * 64, buf ^ 1);
            asm volatile("s_waitcnt vmcnt(4)" ::: "memory");
        } else {
            asm volatile("s_waitcnt vmcnt(0)" ::: "memory");
        }
        __builtin_amdgcn_s_barrier();             // all waves' stage(c) landed
        __builtin_amdgcn_sched_barrier(0);
        for (int kk = 0; kk < 2; ++kk) {
            bf16x8 af[2], bfr[2];
            for (int i = 0; i < 2; ++i) {
                int row = wr + i * 16 + l15;
                af[i] = *(const bf16x8*)&As[buf][row][(kk * 32 + lg * 8) ^ ((row & 7) * 8)];
            }
            for (int j = 0; j < 2; ++j) {
                int row = wc + j * 16 + l15;
                bfr[j] = *(const bf16x8*)&Bs[buf][row][(kk * 32 + lg * 8) ^ ((row & 7) * 8)];
            }
            __builtin_amdgcn_s_setprio(1);
            for (int i = 0; i < 2; ++i)
                for (int j = 0; j < 2; ++j)
                    acc[i][j] = MFMA16(af[i], bfr[j], acc[i][j]);
            __builtin_amdgcn_s_setprio(0);
        }
        __builtin_amdgcn_sched_barrier(0);
        __builtin_amdgcn_s_barrier();             // all waves done reading buf
    }
    for (int j = 0; j < 2; ++j) {
        int col = c0 + wc + j * 16 + l15;
        float bv = ga.bias[col];
        for (int i = 0; i < 2; ++i) {
            int row = r0 + wr + i * 16 + lg * 4;
            for (int r = 0; r < 4; ++r) {
                float val = (acc[i][j][r] + bv) * ga.scale;
                if constexpr (MODE == 0)
                    ((bf16*)ga.C)[(size_t)(row + r) * N + col] = (bf16)val;
                else
                    ((float*)ga.C)[(size_t)(row + r) * N + col] = val;
            }
        }
    }
}

// ------- attention v13: R7-proven loop structure (vmcnt(0) + one barrier) -------
// Block = 4 waves over 64 q-rows. Wave (wq=w>>1, p=w&1): q rows t0+wq*32..+31,
// k-half p of each 64-chunk. Swapped QK: S-regs q=lane&31, k=(r&3)+8*(r>>2)+4*hi.
// bid mapping: xcd = bid&7 keeps K/V L2-local; constant-sum bx permutations
// across slots; s_sleep slot stagger (anti-convoy); hoisted LDS offsets.
__global__ __launch_bounds__(256, 3) void attn_kernel(
    const bf16* __restrict__ Qp, const bf16* __restrict__ Kp,
    const bf16* __restrict__ Vtg, bf16* __restrict__ Ob)
{
    const int bid = blockIdx.x;
    const int xcd = bid & 7;
    const int idx = bid >> 3;            // 0..95
    const int t = idx & 31, s = idx >> 5;
    const int bx = (s == 0) ? (31 - t)
                 : (s == 1) ? ((15 - t) & 31)
                 : (((t << 1) & 31) | (t >> 4));
    const int g = xcd * 3 + s;
    const int t0 = bx * 64;
    const int tid = threadIdx.x, lane = tid & 63, w = tid >> 6;
    const int wq = w >> 1, p = w & 1;
    const int l31 = lane & 31, hi = lane >> 5;

    // anti-convoy stagger: co-resident slots offset ~512*s cycles
    if (s == 1) __builtin_amdgcn_s_sleep(8);
    else if (s == 2) __builtin_amdgcn_s_sleep(16);

    __shared__ __align__(16) char smem[32768];
    bf16* KsE = (bf16*)smem;                 // [2][64][64] d-swizzled
    bf16* VsE = (bf16*)(smem + 16384);       // [2][64][64] V^T, k-swizzled

    const bf16* Qg = Qp + (size_t)g * 131072;
    const bf16* Kg = Kp + (size_t)g * 131072;
    const bf16* Vg = Vtg + (size_t)g * 131072;   // [64][2048]
    bf16* Og = Ob + (size_t)g * 131072;

    // Q B-frags in registers: col=q=l31, k-dim d = m*16 + hi*8 + j
    const int qrow = t0 + wq * 32 + l31;
    bf16x8 qB[4];
    for (int m = 0; m < 4; ++m)
        qB[m] = *(const bf16x8*)&Qg[(size_t)qrow * 64 + m * 16 + hi * 8];

    // staging: wave stages 16 rows (2 gll of 8 rows), pre-swizzled source col
    const int srow = w * 16 + (lane >> 3);
    const int scol = 8 * ((lane & 7) ^ (lane >> 3));
    auto stageK = [&](int ch, int b2) {
        const bf16* src = &Kg[(size_t)(ch * 64 + srow) * 64 + scol];
        bf16* dst = KsE + b2 * 4096 + w * 16 * 64;
        gll16(src, dst);
        gll16(src + 8 * 64, dst + 8 * 64);
    };
    auto stageV = [&](int ch, int b2) {
        const bf16* src = &Vg[(size_t)srow * 2048 + ch * 64 + scol];
        bf16* dst = VsE + b2 * 4096 + w * 16 * 64;
        gll16(src, dst);
        gll16(src + 8 * 2048, dst + 8 * 64);
    };

    stageK(0, 0);
    stageV(0, 0);

    f32x16 oacc0 = {}, oacc1 = {};
    float dsum = 0.f;
    const int qmax = t0 + wq * 32 + 31;                 // wave's q range top
    const int qmin = t0 + wq * 32;
    const int kofs = p * 32;                            // wave's k-half offset
    const int swz = (l31 & 7) * 8;

    // hoisted per-lane LDS element offsets (loop-invariant; buffer = +4096)
    int koff[4], voff0[2], voff1[2];
    for (int m = 0; m < 4; ++m)
        koff[m] = (kofs + l31) * 64 + ((m * 16 + hi * 8) ^ swz);
    for (int kt = 0; kt < 2; ++kt) {
        const int col = (kofs + kt * 16 + hi * 8) ^ swz;
        voff0[kt] = l31 * 64 + col;
        voff1[kt] = (32 + l31) * 64 + col;
    }

    for (int c = 0; c < 32; ++c) {
        const int boff = (c & 1) * 4096;
        asm volatile("s_waitcnt vmcnt(0)" ::: "memory");
        __builtin_amdgcn_s_barrier();
        __builtin_amdgcn_sched_barrier(0);
        if (c < 31) {
            stageK(c + 1, (c & 1) ^ 1);
            if (c + 1 <= bx) stageV(c + 1, (c & 1) ^ 1);
        }
        __builtin_amdgcn_sched_barrier(0);

        const int kc = c * 64;
        const bool activ = (kc + kofs <= qmax);         // wave-uniform
        const bool fullc = (kc + kofs + 31 <= qmin);    // wave-uniform

        // ---- QK^T: A = K rows (wave's 32-k half), B = Q regs
        f32x16 s2 = {};
        __builtin_amdgcn_s_setprio(1);
        for (int m = 0; m < 4; ++m) {
            bf16x8 kf = *(const bf16x8*)&KsE[boff + koff[m]];
            s2 = MFMA32(kf, qB[m], s2);
        }
        __builtin_amdgcn_s_setprio(0);

        // ---- exp2 (Q pre-scaled by log2e/8) + denominator (UNmasked, tree sum)
        float e[16];
        for (int r = 0; r < 16; ++r) e[r] = __builtin_exp2f(s2[r]);
        {
            float p01 = e[0] + e[1],  p23 = e[2] + e[3];
            float p45 = e[4] + e[5],  p67 = e[6] + e[7];
            float p89 = e[8] + e[9],  pab = e[10] + e[11];
            float pcd = e[12] + e[13], pef = e[14] + e[15];
            float q0 = p01 + p23, q1 = p45 + p67, q2 = p89 + pab, q3 = pcd + pef;
            dsum += (q0 + q1) + (q2 + q3);
        }

        if (activ) {
            if (!fullc) {   // diagonal: tril AFTER softmax
                for (int r = 0; r < 16; ++r) {
                    int kg = kc + kofs + (r & 3) + 8 * (r >> 2) + 4 * hi;
                    if (kg > qrow) e[r] = 0.f;
                }
            }
            // ---- pack P to bf16 + permlane32_swap -> 2 PV A-frags, no LDS
            bf16x8 pf[2];
            {
                unsigned a0 = pk_bf16(e[0], e[1]), a1 = pk_bf16(e[2], e[3]);
                unsigned b0 = pk_bf16(e[4], e[5]), b1 = pk_bf16(e[6], e[7]);
                plane32swap(a0, b0); plane32swap(a1, b1);
                pf[0] = frag_words(a0, a1, b0, b1);
                a0 = pk_bf16(e[8], e[9]);   a1 = pk_bf16(e[10], e[11]);
                b0 = pk_bf16(e[12], e[13]); b1 = pk_bf16(e[14], e[15]);
                plane32swap(a0, b0); plane32swap(a1, b1);
                pf[1] = frag_words(a0, a1, b0, b1);
            }
            // ---- PV: A = P frags, B = V^T tile (col d, row k)
            __builtin_amdgcn_s_setprio(1);
            for (int kt = 0; kt < 2; ++kt) {
                bf16x8 v0 = *(const bf16x8*)&VsE[boff + voff0[kt]];
                bf16x8 v1 = *(const bf16x8*)&VsE[boff + voff1[kt]];
                oacc0 = MFMA32(pf[kt], v0, oacc0);
                oacc1 = MFMA32(pf[kt], v1, oacc1);
            }
            __builtin_amdgcn_s_setprio(0);
        }
    }

    // ---- wave-internal k reduce: lane & lane^32 hold complementary k for q=l31
    dsum += __shfl_xor(dsum, 32);

    // ---- cross-pair reduce via LDS overlay (Ks/Vs regions dead after loop)
    __syncthreads();
    float* Ored = (float*)smem;                 // [pair][q 0-31][d 0-63] = 2 x 8KB
    float* dred = (float*)(smem + 16384);       // [wave][q 0-31] = 512 B
    if (l31 == lane) dred[w * 32 + l31] = dsum; // lanes 0-31 only
    if (p == 1) {
        float* Op = Ored + wq * 2048;
        for (int r = 0; r < 16; ++r) {
            const int qoff = (r & 3) + 8 * (r >> 2) + 4 * hi;
            Op[qoff * 64 + l31]      = oacc0[r];
            Op[qoff * 64 + 32 + l31] = oacc1[r];
        }
    }
    __syncthreads();
    if (p == 0) {
        const float dtot = dsum + dred[(w + 1) * 32 + l31];
        const float rall = 1.0f / dtot;          // valid for q=l31 at every lane
        const float* Op = Ored + wq * 2048;
        for (int r = 0; r < 16; ++r) {
            const int qoff = (r & 3) + 8 * (r >> 2) + 4 * hi;
            const float inv = __shfl(rall, qoff);
            const size_t row = (size_t)(t0 + wq * 32 + qoff) * 64;
            Og[row + l31]      = (bf16)((oacc0[r] + Op[qoff * 64 + l31])      * inv);
            Og[row + 32 + l31] = (bf16)((oacc1[r] + Op[qoff * 64 + 32 + l31]) * inv);
        }
    }
}

// ---------------- host ----------------
extern "C" void kernel_launch(void* const* d_in, const int* in_sizes, int n_in,
                              void* d_out, int out_size, void* d_ws, size_t ws_size,
                              hipStream_t stream) {
    const float* query = (const float*)d_in[0];
    const float* key_  = (const float*)d_in[1];
    const float* value = (const float*)d_in[2];
    const float* Wq = (const float*)d_in[3];
    const float* bq = (const float*)d_in[4];
    const float* Wk = (const float*)d_in[5];
    const float* bk = (const float*)d_in[6];
    const float* Wv = (const float*)d_in[7];
    const float* bv = (const float*)d_in[8];
    const float* Wo = (const float*)d_in[9];
    const float* bo = (const float*)d_in[10];
    float* out = (float*)d_out;

    const size_t MN = (size_t)4096 * 768;
    const size_t WW = (size_t)768 * 768;
    bf16* Qp  = (bf16*)d_ws;
    bf16* Kp  = Qp + MN;
    bf16* Vp  = Kp + MN;     // V projection, standard [4096][768] layout
    bf16* Obf = Vp + MN;
    bf16* Vtg = Obf + MN;    // V^T slabs, written by vtrans
    bf16* WtQ = Vtg + MN;
    bf16* WtK = WtQ + WW;
    bf16* WtV = WtK + WW;
    bf16* WtO = WtV + WW;
    bf16* Vb  = WtO + WW;    // +1 MN slab
    // bf16 activation inputs alias slabs that are dead until after gemm<0>:
    bf16* Qb  = Obf;         // Obf written only by attn (after gemm<0> reads Qb)
    bf16* Kb  = Vtg;         // Vtg written by vtrans (after gemm<0> reads Kb)

    prelude<<<dim3(5184), 256, 0, stream>>>(
        query, key_, value, Qb, Kb, Vb,
        TArg{Wq, WtQ}, TArg{Wk, WtK}, TArg{Wv, WtV}, TArg{Wo, WtO});

    // fold log2(e)/sqrt(HD) into Q so attention uses native exp2
    gemm_bt_bias<0><<<dim3(12, 64, 3), 256, 0, stream>>>(
        GArg{Qb, WtQ, bq, Qp, 0.18033688f},
        GArg{Kb, WtK, bk, Kp, 1.0f},
        GArg{Vb, WtV, bv, Vp, 1.0f});

    vtrans<<<dim3(32, 24), 256, 0, stream>>>(Vp, Vtg);

    attn_kernel<<<dim3(768), 256, 0, stream>>>(Qp, Kp, Vtg, Obf);

    gemm_bt_bias<1><<<dim3(12, 64, 1), 256, 0, stream>>>(
        GArg{Obf, WtO, bo, out, 1.0f},
        GArg{Obf, WtO, bo, out, 1.0f},
        GArg{Obf, WtO, bo, out, 1.0f});
}

// Round 14
// 91.262 us; speedup vs baseline: 1.3023x; 1.0965x over previous
//
#include <hip/hip_runtime.h>
#include <hip/hip_bf16.h>

// MultiHeadAttentionLegacy: B=2, S=2048, E=768, H=12, HD=64, G=B*H=24
// Inputs fp32, output fp32; internal bf16 MFMA pipeline.
// Legacy reshape = pure flat re-chunk: [4096][768] buffer == 24 slabs [2048][64].
// Softmax denominator over FULL row; tril mask applied AFTER softmax.
// Q projection pre-scaled by log2(e)/sqrt(64) so attention uses exp2 directly.
//
// R1: pre-convert q/k/v fp32->bf16 (gll staging for both GEMM operands).
// R2 (FAILED): deeper attn LDS pipeline -> worse. Not latency-bound.
// R3 (FAILED): direct per-lane L2 reads -> 2x worse. LDS staging is right.
// R4 (FAILED): fewer rounds via tail-pairing -> slightly worse.
// R5 (WIN): constant-sum bx triplets balance per-CU PV load; XCD-affine GEMM.
// R6 (small WIN): launch_bounds(256,3) + hoisted LDS offsets.
// R7 (small WIN): s_sleep slot stagger (anti-convoy).
// R8/R9 (FAILED): vt-fused V epilogue had wrong legacy mapping.
// R10 (passed, SLOW): correct vt mapping = stride-12 2B scatter. Fused-vt dead.
// R11 (WIN): separate vtrans + prelude fusion banked. 106.6us.
// R12 (small WIN): counted-vmcnt GEMM loop. 105.4us.
// R13 (WIN): 64x64 GEMM tiles -> 9/CU and 3/CU exact dispatch. 100.1us.
// R14: attn VALU audit found a ~4x gap between source-level VALU count
//   (~90 ops/wave-round) and measured VALUBusy (~330 ops) -- prime suspect is
//   __builtin_exp2f expanding through the OCML fixup path instead of a bare
//   v_exp_f32. Swap to __builtin_amdgcn_exp2f (native instruction, <=1 ULP).
//   Single-line A/B: if attn doesn't move, exp2 was already native and this
//   attn structure is at its issue-bound floor.

typedef __bf16 bf16;
typedef __attribute__((ext_vector_type(4))) __bf16 bf16x4;
typedef __attribute__((ext_vector_type(8))) __bf16 bf16x8;
typedef __attribute__((ext_vector_type(4))) float f32x4;
typedef __attribute__((ext_vector_type(16))) float f32x16;
typedef __attribute__((ext_vector_type(4))) unsigned int uint4v;

#define MFMA16(a,b,c) __builtin_amdgcn_mfma_f32_16x16x32_bf16((a),(b),(c),0,0,0)
#define MFMA32(a,b,c) __builtin_amdgcn_mfma_f32_32x32x16_bf16((a),(b),(c),0,0,0)

typedef const __attribute__((address_space(1))) unsigned int GU32;
typedef __attribute__((address_space(3))) unsigned int LU32;

__device__ __forceinline__ void gll16(const void* gsrc, void* ldst) {
    __builtin_amdgcn_global_load_lds((GU32*)gsrc, (LU32*)ldst, 16, 0, 0);
}

__device__ __forceinline__ unsigned pk_bf16(float lo, float hi) {
    unsigned r;
    asm("v_cvt_pk_bf16_f32 %0, %1, %2" : "=v"(r) : "v"(lo), "v"(hi));
    return r;
}

// v_permlane32_swap_b32: a.hi32lanes <-> b.lo32lanes
__device__ __forceinline__ void plane32swap(unsigned &a, unsigned &b) {
    asm("v_permlane32_swap_b32 %0, %1" : "+v"(a), "+v"(b));
}

__device__ __forceinline__ bf16x8 frag_words(unsigned w0, unsigned w1, unsigned w2, unsigned w3) {
    union { unsigned u[4]; bf16x8 v; } f;
    f.u[0] = w0; f.u[1] = w1; f.u[2] = w2; f.u[3] = w3;
    return f.v;
}

// ------- fused prelude: cvt (blocks 0..4607) + weight transpose (4608..5183) -------
struct TArg { const float* in; bf16* out; };

__global__ __launch_bounds__(256) void prelude(
    const float* __restrict__ q, const float* __restrict__ k, const float* __restrict__ v,
    bf16* __restrict__ Qb, bf16* __restrict__ Kb, bf16* __restrict__ Vb,
    TArg a0, TArg a1, TArg a2, TArg a3)
{
    __shared__ bf16 tile[64][72];
    const int b = blockIdx.x;
    const int tid = threadIdx.x;
    if (b < 4608) {
        const int m = b / 1536, xx = b % 1536;
        const float* src = m == 0 ? q : m == 1 ? k : v;
        bf16* dst = m == 0 ? Qb : m == 1 ? Kb : Vb;
        const size_t base = (size_t)xx * 2048 + (size_t)tid * 8;
        f32x4 lo = *(const f32x4*)&src[base];
        f32x4 hi = *(const f32x4*)&src[base + 4];
        bf16x8 o;
        for (int j = 0; j < 4; ++j) { o[j] = (bf16)lo[j]; o[4 + j] = (bf16)hi[j]; }
        *(bf16x8*)&dst[base] = o;
    } else {
        const int bb = b - 4608;                // 0..575
        const int wz = bb / 144, bxy = bb % 144;
        TArg ta = wz == 0 ? a0 : wz == 1 ? a1 : wz == 2 ? a2 : a3;
        const int bx = bxy % 12, by = bxy / 12;
        const int k0 = by * 64, n0 = bx * 64;
        for (int qq = 0; qq < 2; ++qq) {
            int idx = qq * 256 + tid;
            int i = idx >> 3, j0 = (idx & 7) * 8;
            const float* src = &ta.in[(size_t)(k0 + i) * 768 + n0 + j0];
            f32x4 lo = *(const f32x4*)&src[0];
            f32x4 hi = *(const f32x4*)&src[4];
            bf16x8 vv;
            for (int j = 0; j < 4; ++j) { vv[j] = (bf16)lo[j]; vv[4 + j] = (bf16)hi[j]; }
            *(bf16x8*)&tile[i][j0] = vv;
        }
        __syncthreads();
        for (int qq = 0; qq < 2; ++qq) {
            int idx = qq * 256 + tid;
            int n = idx >> 3, j0 = (idx & 7) * 8;
            bf16x8 vv;
            for (int jj = 0; jj < 8; ++jj) vv[jj] = tile[j0 + jj][n];
            *(bf16x8*)&ta.out[(size_t)(n0 + n) * 768 + k0 + j0] = vv;
        }
    }
}

// ------- V slab transpose: Vt[g][d][k] = Vp_flat[g*131072 + k*64 + d] -------
__global__ __launch_bounds__(256) void vtrans(const bf16* __restrict__ Vp, bf16* __restrict__ Vt) {
    __shared__ bf16 tile[64][72];
    const int g = blockIdx.y;
    const int k0 = blockIdx.x * 64;
    const bf16* src = Vp + (size_t)g * 131072;
    bf16* dst = Vt + (size_t)g * 131072;
    const int tid = threadIdx.x;
    for (int q = 0; q < 2; ++q) {
        int idx = q * 256 + tid;
        int r = idx >> 3, c = (idx & 7) * 8;
        *(uint4v*)&tile[r][c] = *(const uint4v*)&src[(size_t)(k0 + r) * 64 + c];
    }
    __syncthreads();
    for (int q = 0; q < 2; ++q) {
        int idx = q * 256 + tid;
        int d = idx >> 3, c = (idx & 7) * 8;
        bf16x8 v;
        for (int j = 0; j < 8; ++j) v[j] = tile[c + j][d];
        *(bf16x8*)&dst[(size_t)d * 2048 + k0 + c] = v;
    }
}

// --- GEMM: C[4096x768] = (A @ Bt^T + bias) * scale.  A is bf16 always.
//     MODE 0: C bf16 (proj);  MODE 1: C fp32 (out)
//     R13: 64x64 tiles. MODE0: 2304 blocks = 9/CU exact; MODE1: 768 = 3/CU.
//     XCD-affine: xcd = flat&7 owns 8 row-blocks, cols fastest. R12
//     counted-vmcnt loop (4 gll/wave -> vmcnt(4)). ---
struct GArg { const bf16* A; const bf16* Bt; const float* bias; void* C; float scale; };

template<int MODE>
__global__ __launch_bounds__(256) void gemm_bt_bias(GArg g0, GArg g1, GArg g2) {
    const int flat = blockIdx.x + 12 * blockIdx.y + 768 * blockIdx.z;
    const int xcd = flat & 7;
    const int idx = flat >> 3;          // z=3: 0..287, z=1: 0..95
    const int mat = idx / 96;
    const int rem = idx % 96;
    const int rloc = rem / 12, colb = rem % 12;
    GArg ga = mat == 0 ? g0 : mat == 1 ? g1 : g2;
    const int K = 768, N = 768;
    __shared__ bf16 As[2][64][64];
    __shared__ bf16 Bs[2][64][64];
    const int tid = threadIdx.x;
    const int lane = tid & 63, wave = tid >> 6;
    const int l15 = lane & 15, lg = lane >> 4;
    const int r0 = (xcd * 8 + rloc) * 64, c0 = colb * 64;
    const int wr = (wave >> 1) * 32, wc = (wave & 1) * 32;
    f32x4 acc[2][2] = {};

    const int grow = lane >> 3;                       // 0..7
    const int gcol = 8 * ((lane & 7) ^ (lane >> 3));  // swizzled col

    auto stage = [&](int kt, int buf) {
        const bf16* srcA = &ga.A[(size_t)(r0 + wave * 16 + grow) * K + kt + gcol];
        gll16(srcA, &As[buf][wave * 16][0]);
        gll16(srcA + 8 * K, &As[buf][wave * 16 + 8][0]);
        const bf16* srcB = &ga.Bt[(size_t)(c0 + wave * 16 + grow) * K + kt + gcol];
        gll16(srcB, &Bs[buf][wave * 16][0]);
        gll16(srcB + 8 * K, &Bs[buf][wave * 16 + 8][0]);
    };

    stage(0, 0);                                  // 4 glls in flight

    for (int c = 0; c < 12; ++c) {
        const int buf = c & 1;
        if (c < 11) {
            stage((c + 1) * 64, buf ^ 1);
            asm volatile("s_waitcnt vmcnt(4)" ::: "memory");
        } else {
            asm volatile("s_waitcnt vmcnt(0)" ::: "memory");
        }
        __builtin_amdgcn_s_barrier();             // all waves' stage(c) landed
        __builtin_amdgcn_sched_barrier(0);
        for (int kk = 0; kk < 2; ++kk) {
            bf16x8 af[2], bfr[2];
            for (int i = 0; i < 2; ++i) {
                int row = wr + i * 16 + l15;
                af[i] = *(const bf16x8*)&As[buf][row][(kk * 32 + lg * 8) ^ ((row & 7) * 8)];
            }
            for (int j = 0; j < 2; ++j) {
                int row = wc + j * 16 + l15;
                bfr[j] = *(const bf16x8*)&Bs[buf][row][(kk * 32 + lg * 8) ^ ((row & 7) * 8)];
            }
            __builtin_amdgcn_s_setprio(1);
            for (int i = 0; i < 2; ++i)
                for (int j = 0; j < 2; ++j)
                    acc[i][j] = MFMA16(af[i], bfr[j], acc[i][j]);
            __builtin_amdgcn_s_setprio(0);
        }
        __builtin_amdgcn_sched_barrier(0);
        __builtin_amdgcn_s_barrier();             // all waves done reading buf
    }
    for (int j = 0; j < 2; ++j) {
        int col = c0 + wc + j * 16 + l15;
        float bv = ga.bias[col];
        for (int i = 0; i < 2; ++i) {
            int row = r0 + wr + i * 16 + lg * 4;
            for (int r = 0; r < 4; ++r) {
                float val = (acc[i][j][r] + bv) * ga.scale;
                if constexpr (MODE == 0)
                    ((bf16*)ga.C)[(size_t)(row + r) * N + col] = (bf16)val;
                else
                    ((float*)ga.C)[(size_t)(row + r) * N + col] = val;
            }
        }
    }
}

// ------- attention v14: v13 + native v_exp_f32 (raw exp2 intrinsic) -------
// Block = 4 waves over 64 q-rows. Wave (wq=w>>1, p=w&1): q rows t0+wq*32..+31,
// k-half p of each 64-chunk. Swapped QK: S-regs q=lane&31, k=(r&3)+8*(r>>2)+4*hi.
// bid mapping: xcd = bid&7 keeps K/V L2-local; constant-sum bx permutations
// across slots; s_sleep slot stagger (anti-convoy); hoisted LDS offsets.
__global__ __launch_bounds__(256, 3) void attn_kernel(
    const bf16* __restrict__ Qp, const bf16* __restrict__ Kp,
    const bf16* __restrict__ Vtg, bf16* __restrict__ Ob)
{
    const int bid = blockIdx.x;
    const int xcd = bid & 7;
    const int idx = bid >> 3;            // 0..95
    const int t = idx & 31, s = idx >> 5;
    const int bx = (s == 0) ? (31 - t)
                 : (s == 1) ? ((15 - t) & 31)
                 : (((t << 1) & 31) | (t >> 4));
    const int g = xcd * 3 + s;
    const int t0 = bx * 64;
    const int tid = threadIdx.x, lane = tid & 63, w = tid >> 6;
    const int wq = w >> 1, p = w & 1;
    const int l31 = lane & 31, hi = lane >> 5;

    // anti-convoy stagger: co-resident slots offset ~512*s cycles
    if (s == 1) __builtin_amdgcn_s_sleep(8);
    else if (s == 2) __builtin_amdgcn_s_sleep(16);

    __shared__ __align__(16) char smem[32768];
    bf16* KsE = (bf16*)smem;                 // [2][64][64] d-swizzled
    bf16* VsE = (bf16*)(smem + 16384);       // [2][64][64] V^T, k-swizzled

    const bf16* Qg = Qp + (size_t)g * 131072;
    const bf16* Kg = Kp + (size_t)g * 131072;
    const bf16* Vg = Vtg + (size_t)g * 131072;   // [64][2048]
    bf16* Og = Ob + (size_t)g * 131072;

    // Q B-frags in registers: col=q=l31, k-dim d = m*16 + hi*8 + j
    const int qrow = t0 + wq * 32 + l31;
    bf16x8 qB[4];
    for (int m = 0; m < 4; ++m)
        qB[m] = *(const bf16x8*)&Qg[(size_t)qrow * 64 + m * 16 + hi * 8];

    // staging: wave stages 16 rows (2 gll of 8 rows), pre-swizzled source col
    const int srow = w * 16 + (lane >> 3);
    const int scol = 8 * ((lane & 7) ^ (lane >> 3));
    auto stageK = [&](int ch, int b2) {
        const bf16* src = &Kg[(size_t)(ch * 64 + srow) * 64 + scol];
        bf16* dst = KsE + b2 * 4096 + w * 16 * 64;
        gll16(src, dst);
        gll16(src + 8 * 64, dst + 8 * 64);
    };
    auto stageV = [&](int ch, int b2) {
        const bf16* src = &Vg[(size_t)srow * 2048 + ch * 64 + scol];
        bf16* dst = VsE + b2 * 4096 + w * 16 * 64;
        gll16(src, dst);
        gll16(src + 8 * 2048, dst + 8 * 64);
    };

    stageK(0, 0);
    stageV(0, 0);

    f32x16 oacc0 = {}, oacc1 = {};
    float dsum = 0.f;
    const int qmax = t0 + wq * 32 + 31;                 // wave's q range top
    const int qmin = t0 + wq * 32;
    const int kofs = p * 32;                            // wave's k-half offset
    const int swz = (l31 & 7) * 8;

    // hoisted per-lane LDS element offsets (loop-invariant; buffer = +4096)
    int koff[4], voff0[2], voff1[2];
    for (int m = 0; m < 4; ++m)
        koff[m] = (kofs + l31) * 64 + ((m * 16 + hi * 8) ^ swz);
    for (int kt = 0; kt < 2; ++kt) {
        const int col = (kofs + kt * 16 + hi * 8) ^ swz;
        voff0[kt] = l31 * 64 + col;
        voff1[kt] = (32 + l31) * 64 + col;
    }

    for (int c = 0; c < 32; ++c) {
        const int boff = (c & 1) * 4096;
        asm volatile("s_waitcnt vmcnt(0)" ::: "memory");
        __builtin_amdgcn_s_barrier();
        __builtin_amdgcn_sched_barrier(0);
        if (c < 31) {
            stageK(c + 1, (c & 1) ^ 1);
            if (c + 1 <= bx) stageV(c + 1, (c & 1) ^ 1);
        }
        __builtin_amdgcn_sched_barrier(0);

        const int kc = c * 64;
        const bool activ = (kc + kofs <= qmax);         // wave-uniform
        const bool fullc = (kc + kofs + 31 <= qmin);    // wave-uniform

        // ---- QK^T: A = K rows (wave's 32-k half), B = Q regs
        f32x16 s2 = {};
        __builtin_amdgcn_s_setprio(1);
        for (int m = 0; m < 4; ++m) {
            bf16x8 kf = *(const bf16x8*)&KsE[boff + koff[m]];
            s2 = MFMA32(kf, qB[m], s2);
        }
        __builtin_amdgcn_s_setprio(0);

        // ---- native exp2 (Q pre-scaled by log2e/8) + denominator (tree sum)
        float e[16];
        for (int r = 0; r < 16; ++r) e[r] = __builtin_amdgcn_exp2f(s2[r]);
        {
            float p01 = e[0] + e[1],  p23 = e[2] + e[3];
            float p45 = e[4] + e[5],  p67 = e[6] + e[7];
            float p89 = e[8] + e[9],  pab = e[10] + e[11];
            float pcd = e[12] + e[13], pef = e[14] + e[15];
            float q0 = p01 + p23, q1 = p45 + p67, q2 = p89 + pab, q3 = pcd + pef;
            dsum += (q0 + q1) + (q2 + q3);
        }

        if (activ) {
            if (!fullc) {   // diagonal: tril AFTER softmax
                for (int r = 0; r < 16; ++r) {
                    int kg = kc + kofs + (r & 3) + 8 * (r >> 2) + 4 * hi;
                    if (kg > qrow) e[r] = 0.f;
                }
            }
            // ---- pack P to bf16 + permlane32_swap -> 2 PV A-frags, no LDS
            bf16x8 pf[2];
            {
                unsigned a0 = pk_bf16(e[0], e[1]), a1 = pk_bf16(e[2], e[3]);
                unsigned b0 = pk_bf16(e[4], e[5]), b1 = pk_bf16(e[6], e[7]);
                plane32swap(a0, b0); plane32swap(a1, b1);
                pf[0] = frag_words(a0, a1, b0, b1);
                a0 = pk_bf16(e[8], e[9]);   a1 = pk_bf16(e[10], e[11]);
                b0 = pk_bf16(e[12], e[13]); b1 = pk_bf16(e[14], e[15]);
                plane32swap(a0, b0); plane32swap(a1, b1);
                pf[1] = frag_words(a0, a1, b0, b1);
            }
            // ---- PV: A = P frags, B = V^T tile (col d, row k)
            __builtin_amdgcn_s_setprio(1);
            for (int kt = 0; kt < 2; ++kt) {
                bf16x8 v0 = *(const bf16x8*)&VsE[boff + voff0[kt]];
                bf16x8 v1 = *(const bf16x8*)&VsE[boff + voff1[kt]];
                oacc0 = MFMA32(pf[kt], v0, oacc0);
                oacc1 = MFMA32(pf[kt], v1, oacc1);
            }
            __builtin_amdgcn_s_setprio(0);
        }
    }

    // ---- wave-internal k reduce: lane & lane^32 hold complementary k for q=l31
    dsum += __shfl_xor(dsum, 32);

    // ---- cross-pair reduce via LDS overlay (Ks/Vs regions dead after loop)
    __syncthreads();
    float* Ored = (float*)smem;                 // [pair][q 0-31][d 0-63] = 2 x 8KB
    float* dred = (float*)(smem + 16384);       // [wave][q 0-31] = 512 B
    if (l31 == lane) dred[w * 32 + l31] = dsum; // lanes 0-31 only
    if (p == 1) {
        float* Op = Ored + wq * 2048;
        for (int r = 0; r < 16; ++r) {
            const int qoff = (r & 3) + 8 * (r >> 2) + 4 * hi;
            Op[qoff * 64 + l31]      = oacc0[r];
            Op[qoff * 64 + 32 + l31] = oacc1[r];
        }
    }
    __syncthreads();
    if (p == 0) {
        const float dtot = dsum + dred[(w + 1) * 32 + l31];
        const float rall = 1.0f / dtot;          // valid for q=l31 at every lane
        const float* Op = Ored + wq * 2048;
        for (int r = 0; r < 16; ++r) {
            const int qoff = (r & 3) + 8 * (r >> 2) + 4 * hi;
            const float inv = __shfl(rall, qoff);
            const size_t row = (size_t)(t0 + wq * 32 + qoff) * 64;
            Og[row + l31]      = (bf16)((oacc0[r] + Op[qoff * 64 + l31])      * inv);
            Og[row + 32 + l31] = (bf16)((oacc1[r] + Op[qoff * 64 + 32 + l31]) * inv);
        }
    }
}

// ---------------- host ----------------
extern "C" void kernel_launch(void* const* d_in, const int* in_sizes, int n_in,
                              void* d_out, int out_size, void* d_ws, size_t ws_size,
                              hipStream_t stream) {
    const float* query = (const float*)d_in[0];
    const float* key_  = (const float*)d_in[1];
    const float* value = (const float*)d_in[2];
    const float* Wq = (const float*)d_in[3];
    const float* bq = (const float*)d_in[4];
    const float* Wk = (const float*)d_in[5];
    const float* bk = (const float*)d_in[6];
    const float* Wv = (const float*)d_in[7];
    const float* bv = (const float*)d_in[8];
    const float* Wo = (const float*)d_in[9];
    const float* bo = (const float*)d_in[10];
    float* out = (float*)d_out;

    const size_t MN = (size_t)4096 * 768;
    const size_t WW = (size_t)768 * 768;
    bf16* Qp  = (bf16*)d_ws;
    bf16* Kp  = Qp + MN;
    bf16* Vp  = Kp + MN;     // V projection, standard [4096][768] layout
    bf16* Obf = Vp + MN;
    bf16* Vtg = Obf + MN;    // V^T slabs, written by vtrans
    bf16* WtQ = Vtg + MN;
    bf16* WtK = WtQ + WW;
    bf16* WtV = WtK + WW;
    bf16* WtO = WtV + WW;
    bf16* Vb  = WtO + WW;    // +1 MN slab
    // bf16 activation inputs alias slabs that are dead until after gemm<0>:
    bf16* Qb  = Obf;         // Obf written only by attn (after gemm<0> reads Qb)
    bf16* Kb  = Vtg;         // Vtg written by vtrans (after gemm<0> reads Kb)

    prelude<<<dim3(5184), 256, 0, stream>>>(
        query, key_, value, Qb, Kb, Vb,
        TArg{Wq, WtQ}, TArg{Wk, WtK}, TArg{Wv, WtV}, TArg{Wo, WtO});

    // fold log2(e)/sqrt(HD) into Q so attention uses native exp2
    gemm_bt_bias<0><<<dim3(12, 64, 3), 256, 0, stream>>>(
        GArg{Qb, WtQ, bq, Qp, 0.18033688f},
        GArg{Kb, WtK, bk, Kp, 1.0f},
        GArg{Vb, WtV, bv, Vp, 1.0f});

    vtrans<<<dim3(32, 24), 256, 0, stream>>>(Vp, Vtg);

    attn_kernel<<<dim3(768), 256, 0, stream>>>(Qp, Kp, Vtg, Obf);

    gemm_bt_bias<1><<<dim3(12, 64, 1), 256, 0, stream>>>(
        GArg{Obf, WtO, bo, out, 1.0f},
        GArg{Obf, WtO, bo, out, 1.0f},
        GArg{Obf, WtO, bo, out, 1.0f});
}

// Round 15
// 91.102 us; speedup vs baseline: 1.3046x; 1.0018x over previous
//
#include <hip/hip_runtime.h>
#include <hip/hip_bf16.h>

// MultiHeadAttentionLegacy: B=2, S=2048, E=768, H=12, HD=64, G=B*H=24
// Inputs fp32, output fp32; internal bf16 MFMA pipeline.
// Legacy reshape = pure flat re-chunk: [4096][768] buffer == 24 slabs [2048][64].
// Softmax denominator over FULL row; tril mask applied AFTER softmax.
// Q projection pre-scaled by log2(e)/sqrt(64) so attention uses exp2 directly.
//
// R1: pre-convert q/k/v fp32->bf16 (gll staging for both GEMM operands).
// R2 (FAILED): deeper attn LDS pipeline -> worse. Not latency-bound.
// R3 (FAILED): direct per-lane L2 reads -> 2x worse. LDS staging is right.
// R4 (FAILED): fewer rounds via tail-pairing -> slightly worse.
// R5 (WIN): constant-sum bx triplets balance per-CU PV load; XCD-affine GEMM.
// R6 (small WIN): launch_bounds(256,3) + hoisted LDS offsets.
// R7 (small WIN): s_sleep slot stagger (anti-convoy).
// R8/R9 (FAILED): vt-fused V epilogue had wrong legacy mapping (bisect proved
//   the counted-vmcnt loops were NOT the bug).
// R10 (passed, SLOW): correct vt mapping = stride-12 2B scatter. Fused-vt dead.
// R11 (WIN): separate vtrans + prelude fusion banked. 106.6us.
// R12 (small WIN): counted-vmcnt GEMM loop (isolated retry -> correct). 105.4us.
// R13 (WIN): 64x64 GEMM tiles -> 9/CU and 3/CU exact dispatch. 100.1us.
// R14 (WIN): native v_exp_f32 (__builtin_amdgcn_exp2f) -- OCML expansion was
//   ~4x the VALU budget. 91.3us; attn ~41us.
// R15: finish the R8 bisect -- attn counted-vmcnt loop, isolated. Stage(c+1)
//   first, wait only chunk c's own glls: vmcnt(4) causal / vmcnt(2) tail
//   (boundary c==bx: 4 old + 2 new = 6, vmcnt(2) drains exactly the old 4) /
//   vmcnt(0) last. Two barriers bracket the LDS buffer lifetime.

typedef __bf16 bf16;
typedef __attribute__((ext_vector_type(4))) __bf16 bf16x4;
typedef __attribute__((ext_vector_type(8))) __bf16 bf16x8;
typedef __attribute__((ext_vector_type(4))) float f32x4;
typedef __attribute__((ext_vector_type(16))) float f32x16;
typedef __attribute__((ext_vector_type(4))) unsigned int uint4v;

#define MFMA16(a,b,c) __builtin_amdgcn_mfma_f32_16x16x32_bf16((a),(b),(c),0,0,0)
#define MFMA32(a,b,c) __builtin_amdgcn_mfma_f32_32x32x16_bf16((a),(b),(c),0,0,0)

typedef const __attribute__((address_space(1))) unsigned int GU32;
typedef __attribute__((address_space(3))) unsigned int LU32;

__device__ __forceinline__ void gll16(const void* gsrc, void* ldst) {
    __builtin_amdgcn_global_load_lds((GU32*)gsrc, (LU32*)ldst, 16, 0, 0);
}

__device__ __forceinline__ unsigned pk_bf16(float lo, float hi) {
    unsigned r;
    asm("v_cvt_pk_bf16_f32 %0, %1, %2" : "=v"(r) : "v"(lo), "v"(hi));
    return r;
}

// v_permlane32_swap_b32: a.hi32lanes <-> b.lo32lanes
__device__ __forceinline__ void plane32swap(unsigned &a, unsigned &b) {
    asm("v_permlane32_swap_b32 %0, %1" : "+v"(a), "+v"(b));
}

__device__ __forceinline__ bf16x8 frag_words(unsigned w0, unsigned w1, unsigned w2, unsigned w3) {
    union { unsigned u[4]; bf16x8 v; } f;
    f.u[0] = w0; f.u[1] = w1; f.u[2] = w2; f.u[3] = w3;
    return f.v;
}

// ------- fused prelude: cvt (blocks 0..4607) + weight transpose (4608..5183) -------
struct TArg { const float* in; bf16* out; };

__global__ __launch_bounds__(256) void prelude(
    const float* __restrict__ q, const float* __restrict__ k, const float* __restrict__ v,
    bf16* __restrict__ Qb, bf16* __restrict__ Kb, bf16* __restrict__ Vb,
    TArg a0, TArg a1, TArg a2, TArg a3)
{
    __shared__ bf16 tile[64][72];
    const int b = blockIdx.x;
    const int tid = threadIdx.x;
    if (b < 4608) {
        const int m = b / 1536, xx = b % 1536;
        const float* src = m == 0 ? q : m == 1 ? k : v;
        bf16* dst = m == 0 ? Qb : m == 1 ? Kb : Vb;
        const size_t base = (size_t)xx * 2048 + (size_t)tid * 8;
        f32x4 lo = *(const f32x4*)&src[base];
        f32x4 hi = *(const f32x4*)&src[base + 4];
        bf16x8 o;
        for (int j = 0; j < 4; ++j) { o[j] = (bf16)lo[j]; o[4 + j] = (bf16)hi[j]; }
        *(bf16x8*)&dst[base] = o;
    } else {
        const int bb = b - 4608;                // 0..575
        const int wz = bb / 144, bxy = bb % 144;
        TArg ta = wz == 0 ? a0 : wz == 1 ? a1 : wz == 2 ? a2 : a3;
        const int bx = bxy % 12, by = bxy / 12;
        const int k0 = by * 64, n0 = bx * 64;
        for (int qq = 0; qq < 2; ++qq) {
            int idx = qq * 256 + tid;
            int i = idx >> 3, j0 = (idx & 7) * 8;
            const float* src = &ta.in[(size_t)(k0 + i) * 768 + n0 + j0];
            f32x4 lo = *(const f32x4*)&src[0];
            f32x4 hi = *(const f32x4*)&src[4];
            bf16x8 vv;
            for (int j = 0; j < 4; ++j) { vv[j] = (bf16)lo[j]; vv[4 + j] = (bf16)hi[j]; }
            *(bf16x8*)&tile[i][j0] = vv;
        }
        __syncthreads();
        for (int qq = 0; qq < 2; ++qq) {
            int idx = qq * 256 + tid;
            int n = idx >> 3, j0 = (idx & 7) * 8;
            bf16x8 vv;
            for (int jj = 0; jj < 8; ++jj) vv[jj] = tile[j0 + jj][n];
            *(bf16x8*)&ta.out[(size_t)(n0 + n) * 768 + k0 + j0] = vv;
        }
    }
}

// ------- V slab transpose: Vt[g][d][k] = Vp_flat[g*131072 + k*64 + d] -------
__global__ __launch_bounds__(256) void vtrans(const bf16* __restrict__ Vp, bf16* __restrict__ Vt) {
    __shared__ bf16 tile[64][72];
    const int g = blockIdx.y;
    const int k0 = blockIdx.x * 64;
    const bf16* src = Vp + (size_t)g * 131072;
    bf16* dst = Vt + (size_t)g * 131072;
    const int tid = threadIdx.x;
    for (int q = 0; q < 2; ++q) {
        int idx = q * 256 + tid;
        int r = idx >> 3, c = (idx & 7) * 8;
        *(uint4v*)&tile[r][c] = *(const uint4v*)&src[(size_t)(k0 + r) * 64 + c];
    }
    __syncthreads();
    for (int q = 0; q < 2; ++q) {
        int idx = q * 256 + tid;
        int d = idx >> 3, c = (idx & 7) * 8;
        bf16x8 v;
        for (int j = 0; j < 8; ++j) v[j] = tile[c + j][d];
        *(bf16x8*)&dst[(size_t)d * 2048 + k0 + c] = v;
    }
}

// --- GEMM: C[4096x768] = (A @ Bt^T + bias) * scale.  A is bf16 always.
//     MODE 0: C bf16 (proj);  MODE 1: C fp32 (out)
//     R13: 64x64 tiles. MODE0: 2304 blocks = 9/CU exact; MODE1: 768 = 3/CU.
//     XCD-affine: xcd = flat&7 owns 8 row-blocks, cols fastest. R12
//     counted-vmcnt loop (4 gll/wave -> vmcnt(4)). ---
struct GArg { const bf16* A; const bf16* Bt; const float* bias; void* C; float scale; };

template<int MODE>
__global__ __launch_bounds__(256) void gemm_bt_bias(GArg g0, GArg g1, GArg g2) {
    const int flat = blockIdx.x + 12 * blockIdx.y + 768 * blockIdx.z;
    const int xcd = flat & 7;
    const int idx = flat >> 3;          // z=3: 0..287, z=1: 0..95
    const int mat = idx / 96;
    const int rem = idx % 96;
    const int rloc = rem / 12, colb = rem % 12;
    GArg ga = mat == 0 ? g0 : mat == 1 ? g1 : g2;
    const int K = 768, N = 768;
    __shared__ bf16 As[2][64][64];
    __shared__ bf16 Bs[2][64][64];
    const int tid = threadIdx.x;
    const int lane = tid & 63, wave = tid >> 6;
    const int l15 = lane & 15, lg = lane >> 4;
    const int r0 = (xcd * 8 + rloc) * 64, c0 = colb * 64;
    const int wr = (wave >> 1) * 32, wc = (wave & 1) * 32;
    f32x4 acc[2][2] = {};

    const int grow = lane >> 3;                       // 0..7
    const int gcol = 8 * ((lane & 7) ^ (lane >> 3));  // swizzled col

    auto stage = [&](int kt, int buf) {
        const bf16* srcA = &ga.A[(size_t)(r0 + wave * 16 + grow) * K + kt + gcol];
        gll16(srcA, &As[buf][wave * 16][0]);
        gll16(srcA + 8 * K, &As[buf][wave * 16 + 8][0]);
        const bf16* srcB = &ga.Bt[(size_t)(c0 + wave * 16 + grow) * K + kt + gcol];
        gll16(srcB, &Bs[buf][wave * 16][0]);
        gll16(srcB + 8 * K, &Bs[buf][wave * 16 + 8][0]);
    };

    stage(0, 0);                                  // 4 glls in flight

    for (int c = 0; c < 12; ++c) {
        const int buf = c & 1;
        if (c < 11) {
            stage((c + 1) * 64, buf ^ 1);
            asm volatile("s_waitcnt vmcnt(4)" ::: "memory");
        } else {
            asm volatile("s_waitcnt vmcnt(0)" ::: "memory");
        }
        __builtin_amdgcn_s_barrier();             // all waves' stage(c) landed
        __builtin_amdgcn_sched_barrier(0);
        for (int kk = 0; kk < 2; ++kk) {
            bf16x8 af[2], bfr[2];
            for (int i = 0; i < 2; ++i) {
                int row = wr + i * 16 + l15;
                af[i] = *(const bf16x8*)&As[buf][row][(kk * 32 + lg * 8) ^ ((row & 7) * 8)];
            }
            for (int j = 0; j < 2; ++j) {
                int row = wc + j * 16 + l15;
                bfr[j] = *(const bf16x8*)&Bs[buf][row][(kk * 32 + lg * 8) ^ ((row & 7) * 8)];
            }
            __builtin_amdgcn_s_setprio(1);
            for (int i = 0; i < 2; ++i)
                for (int j = 0; j < 2; ++j)
                    acc[i][j] = MFMA16(af[i], bfr[j], acc[i][j]);
            __builtin_amdgcn_s_setprio(0);
        }
        __builtin_amdgcn_sched_barrier(0);
        __builtin_amdgcn_s_barrier();             // all waves done reading buf
    }
    for (int j = 0; j < 2; ++j) {
        int col = c0 + wc + j * 16 + l15;
        float bv = ga.bias[col];
        for (int i = 0; i < 2; ++i) {
            int row = r0 + wr + i * 16 + lg * 4;
            for (int r = 0; r < 4; ++r) {
                float val = (acc[i][j][r] + bv) * ga.scale;
                if constexpr (MODE == 0)
                    ((bf16*)ga.C)[(size_t)(row + r) * N + col] = (bf16)val;
                else
                    ((float*)ga.C)[(size_t)(row + r) * N + col] = val;
            }
        }
    }
}

// ------- attention v15: v14 + counted-vmcnt loop (isolated R8 retry) -------
// Block = 4 waves over 64 q-rows. Wave (wq=w>>1, p=w&1): q rows t0+wq*32..+31,
// k-half p of each 64-chunk. Swapped QK: S-regs q=lane&31, k=(r&3)+8*(r>>2)+4*hi.
// Stage(c+1) first; wait only chunk c's own glls (vmcnt(4)/(2)/(0)); barrier;
// compute; end barrier protects buf reuse (iter c+1 stages into iter c's buf).
__global__ __launch_bounds__(256, 3) void attn_kernel(
    const bf16* __restrict__ Qp, const bf16* __restrict__ Kp,
    const bf16* __restrict__ Vtg, bf16* __restrict__ Ob)
{
    const int bid = blockIdx.x;
    const int xcd = bid & 7;
    const int idx = bid >> 3;            // 0..95
    const int t = idx & 31, s = idx >> 5;
    const int bx = (s == 0) ? (31 - t)
                 : (s == 1) ? ((15 - t) & 31)
                 : (((t << 1) & 31) | (t >> 4));
    const int g = xcd * 3 + s;
    const int t0 = bx * 64;
    const int tid = threadIdx.x, lane = tid & 63, w = tid >> 6;
    const int wq = w >> 1, p = w & 1;
    const int l31 = lane & 31, hi = lane >> 5;

    // anti-convoy stagger: co-resident slots offset ~512*s cycles
    if (s == 1) __builtin_amdgcn_s_sleep(8);
    else if (s == 2) __builtin_amdgcn_s_sleep(16);

    __shared__ __align__(16) char smem[32768];
    bf16* KsE = (bf16*)smem;                 // [2][64][64] d-swizzled
    bf16* VsE = (bf16*)(smem + 16384);       // [2][64][64] V^T, k-swizzled

    const bf16* Qg = Qp + (size_t)g * 131072;
    const bf16* Kg = Kp + (size_t)g * 131072;
    const bf16* Vg = Vtg + (size_t)g * 131072;   // [64][2048]
    bf16* Og = Ob + (size_t)g * 131072;

    // Q B-frags in registers: col=q=l31, k-dim d = m*16 + hi*8 + j
    const int qrow = t0 + wq * 32 + l31;
    bf16x8 qB[4];
    for (int m = 0; m < 4; ++m)
        qB[m] = *(const bf16x8*)&Qg[(size_t)qrow * 64 + m * 16 + hi * 8];

    // staging: wave stages 16 rows (2 gll of 8 rows), pre-swizzled source col
    const int srow = w * 16 + (lane >> 3);
    const int scol = 8 * ((lane & 7) ^ (lane >> 3));
    auto stageK = [&](int ch, int b2) {
        const bf16* src = &Kg[(size_t)(ch * 64 + srow) * 64 + scol];
        bf16* dst = KsE + b2 * 4096 + w * 16 * 64;
        gll16(src, dst);
        gll16(src + 8 * 64, dst + 8 * 64);
    };
    auto stageV = [&](int ch, int b2) {
        const bf16* src = &Vg[(size_t)srow * 2048 + ch * 64 + scol];
        bf16* dst = VsE + b2 * 4096 + w * 16 * 64;
        gll16(src, dst);
        gll16(src + 8 * 2048, dst + 8 * 64);
    };

    stageK(0, 0);
    stageV(0, 0);

    f32x16 oacc0 = {}, oacc1 = {};
    float dsum = 0.f;
    const int qmax = t0 + wq * 32 + 31;                 // wave's q range top
    const int qmin = t0 + wq * 32;
    const int kofs = p * 32;                            // wave's k-half offset
    const int swz = (l31 & 7) * 8;

    // hoisted per-lane LDS element offsets (loop-invariant; buffer = +4096)
    int koff[4], voff0[2], voff1[2];
    for (int m = 0; m < 4; ++m)
        koff[m] = (kofs + l31) * 64 + ((m * 16 + hi * 8) ^ swz);
    for (int kt = 0; kt < 2; ++kt) {
        const int col = (kofs + kt * 16 + hi * 8) ^ swz;
        voff0[kt] = l31 * 64 + col;
        voff1[kt] = (32 + l31) * 64 + col;
    }

    for (int c = 0; c < 32; ++c) {
        const int boff = (c & 1) * 4096;
        // stage next chunk FIRST (prev end-barrier guarantees buf^1 is free)
        if (c < 31) {
            stageK(c + 1, (c & 1) ^ 1);
            if (c + 1 <= bx) stageV(c + 1, (c & 1) ^ 1);
        }
        // wait only for chunk c's own loads; chunk c+1's stay in flight.
        // causal chunk c (c<=bx incl. boundary): 4 old glls -> vmcnt leaves the new ones.
        if (c == 31)          asm volatile("s_waitcnt vmcnt(0)" ::: "memory");
        else if (c + 1 <= bx) asm volatile("s_waitcnt vmcnt(4)" ::: "memory");
        else                  asm volatile("s_waitcnt vmcnt(2)" ::: "memory");
        __builtin_amdgcn_s_barrier();
        __builtin_amdgcn_sched_barrier(0);

        const int kc = c * 64;
        const bool activ = (kc + kofs <= qmax);         // wave-uniform
        const bool fullc = (kc + kofs + 31 <= qmin);    // wave-uniform

        // ---- QK^T: A = K rows (wave's 32-k half), B = Q regs
        f32x16 s2 = {};
        __builtin_amdgcn_s_setprio(1);
        for (int m = 0; m < 4; ++m) {
            bf16x8 kf = *(const bf16x8*)&KsE[boff + koff[m]];
            s2 = MFMA32(kf, qB[m], s2);
        }
        __builtin_amdgcn_s_setprio(0);

        // ---- native exp2 (Q pre-scaled by log2e/8) + denominator (tree sum)
        float e[16];
        for (int r = 0; r < 16; ++r) e[r] = __builtin_amdgcn_exp2f(s2[r]);
        {
            float p01 = e[0] + e[1],  p23 = e[2] + e[3];
            float p45 = e[4] + e[5],  p67 = e[6] + e[7];
            float p89 = e[8] + e[9],  pab = e[10] + e[11];
            float pcd = e[12] + e[13], pef = e[14] + e[15];
            float q0 = p01 + p23, q1 = p45 + p67, q2 = p89 + pab, q3 = pcd + pef;
            dsum += (q0 + q1) + (q2 + q3);
        }

        if (activ) {
            if (!fullc) {   // diagonal: tril AFTER softmax
                for (int r = 0; r < 16; ++r) {
                    int kg = kc + kofs + (r & 3) + 8 * (r >> 2) + 4 * hi;
                    if (kg > qrow) e[r] = 0.f;
                }
            }
            // ---- pack P to bf16 + permlane32_swap -> 2 PV A-frags, no LDS
            bf16x8 pf[2];
            {
                unsigned a0 = pk_bf16(e[0], e[1]), a1 = pk_bf16(e[2], e[3]);
                unsigned b0 = pk_bf16(e[4], e[5]), b1 = pk_bf16(e[6], e[7]);
                plane32swap(a0, b0); plane32swap(a1, b1);
                pf[0] = frag_words(a0, a1, b0, b1);
                a0 = pk_bf16(e[8], e[9]);   a1 = pk_bf16(e[10], e[11]);
                b0 = pk_bf16(e[12], e[13]); b1 = pk_bf16(e[14], e[15]);
                plane32swap(a0, b0); plane32swap(a1, b1);
                pf[1] = frag_words(a0, a1, b0, b1);
            }
            // ---- PV: A = P frags, B = V^T tile (col d, row k)
            __builtin_amdgcn_s_setprio(1);
            for (int kt = 0; kt < 2; ++kt) {
                bf16x8 v0 = *(const bf16x8*)&VsE[boff + voff0[kt]];
                bf16x8 v1 = *(const bf16x8*)&VsE[boff + voff1[kt]];
                oacc0 = MFMA32(pf[kt], v0, oacc0);
                oacc1 = MFMA32(pf[kt], v1, oacc1);
            }
            __builtin_amdgcn_s_setprio(0);
        }
        __builtin_amdgcn_sched_barrier(0);
        __builtin_amdgcn_s_barrier();   // all waves done reading buf before next stage
    }

    // ---- wave-internal k reduce: lane & lane^32 hold complementary k for q=l31
    dsum += __shfl_xor(dsum, 32);

    // ---- cross-pair reduce via LDS overlay (Ks/Vs regions dead after loop)
    __syncthreads();
    float* Ored = (float*)smem;                 // [pair][q 0-31][d 0-63] = 2 x 8KB
    float* dred = (float*)(smem + 16384);       // [wave][q 0-31] = 512 B
    if (l31 == lane) dred[w * 32 + l31] = dsum; // lanes 0-31 only
    if (p == 1) {
        float* Op = Ored + wq * 2048;
        for (int r = 0; r < 16; ++r) {
            const int qoff = (r & 3) + 8 * (r >> 2) + 4 * hi;
            Op[qoff * 64 + l31]      = oacc0[r];
            Op[qoff * 64 + 32 + l31] = oacc1[r];
        }
    }
    __syncthreads();
    if (p == 0) {
        const float dtot = dsum + dred[(w + 1) * 32 + l31];
        const float rall = 1.0f / dtot;          // valid for q=l31 at every lane
        const float* Op = Ored + wq * 2048;
        for (int r = 0; r < 16; ++r) {
            const int qoff = (r & 3) + 8 * (r >> 2) + 4 * hi;
            const float inv = __shfl(rall, qoff);
            const size_t row = (size_t)(t0 + wq * 32 + qoff) * 64;
            Og[row + l31]      = (bf16)((oacc0[r] + Op[qoff * 64 + l31])      * inv);
            Og[row + 32 + l31] = (bf16)((oacc1[r] + Op[qoff * 64 + 32 + l31]) * inv);
        }
    }
}

// ---------------- host ----------------
extern "C" void kernel_launch(void* const* d_in, const int* in_sizes, int n_in,
                              void* d_out, int out_size, void* d_ws, size_t ws_size,
                              hipStream_t stream) {
    const float* query = (const float*)d_in[0];
    const float* key_  = (const float*)d_in[1];
    const float* value = (const float*)d_in[2];
    const float* Wq = (const float*)d_in[3];
    const float* bq = (const float*)d_in[4];
    const float* Wk = (const float*)d_in[5];
    const float* bk = (const float*)d_in[6];
    const float* Wv = (const float*)d_in[7];
    const float* bv = (const float*)d_in[8];
    const float* Wo = (const float*)d_in[9];
    const float* bo = (const float*)d_in[10];
    float* out = (float*)d_out;

    const size_t MN = (size_t)4096 * 768;
    const size_t WW = (size_t)768 * 768;
    bf16* Qp  = (bf16*)d_ws;
    bf16* Kp  = Qp + MN;
    bf16* Vp  = Kp + MN;     // V projection, standard [4096][768] layout
    bf16* Obf = Vp + MN;
    bf16* Vtg = Obf + MN;    // V^T slabs, written by vtrans
    bf16* WtQ = Vtg + MN;
    bf16* WtK = WtQ + WW;
    bf16* WtV = WtK + WW;
    bf16* WtO = WtV + WW;
    bf16* Vb  = WtO + WW;    // +1 MN slab
    // bf16 activation inputs alias slabs that are dead until after gemm<0>:
    bf16* Qb  = Obf;         // Obf written only by attn (after gemm<0> reads Qb)
    bf16* Kb  = Vtg;         // Vtg written by vtrans (after gemm<0> reads Kb)

    prelude<<<dim3(5184), 256, 0, stream>>>(
        query, key_, value, Qb, Kb, Vb,
        TArg{Wq, WtQ}, TArg{Wk, WtK}, TArg{Wv, WtV}, TArg{Wo, WtO});

    // fold log2(e)/sqrt(HD) into Q so attention uses native exp2
    gemm_bt_bias<0><<<dim3(12, 64, 3), 256, 0, stream>>>(
        GArg{Qb, WtQ, bq, Qp, 0.18033688f},
        GArg{Kb, WtK, bk, Kp, 1.0f},
        GArg{Vb, WtV, bv, Vp, 1.0f});

    vtrans<<<dim3(32, 24), 256, 0, stream>>>(Vp, Vtg);

    attn_kernel<<<dim3(768), 256, 0, stream>>>(Qp, Kp, Vtg, Obf);

    gemm_bt_bias<1><<<dim3(12, 64, 1), 256, 0, stream>>>(
        GArg{Obf, WtO, bo, out, 1.0f},
        GArg{Obf, WtO, bo, out, 1.0f},
        GArg{Obf, WtO, bo, out, 1.0f});
}